// Round 7
// baseline (589.040 us; speedup 1.0000x reference)
//
#include <hip/hip_runtime.h>
#include <hip/hip_fp16.h>
#include <cstdint>
#include <cstddef>

#define NNODES 100000
#define NEDGES 1600000
#define NGRAPH 1024

// bucketized CSR build
#define BK 256                             // nodes per bucket (dst >> 8)
#define NBUCKET 391                        // ceil(NNODES / BK)
#define CHUNK 4096
#define NCHUNK 391                         // ceil(NEDGES / CHUNK)
#define NBE (NBUCKET * NCHUNK)             // 152881 count-matrix entries

typedef __attribute__((ext_vector_type(8))) short short8;
typedef __attribute__((ext_vector_type(8))) unsigned short ushort8;
typedef __attribute__((ext_vector_type(4))) float f32x4;

__device__ inline float b2f(unsigned short u) {
  return __uint_as_float(((unsigned int)u) << 16);
}
__device__ inline unsigned short f2b(float f) {
  unsigned int x = __float_as_uint(f);
  x += 0x7fffu + ((x >> 16) & 1u);          // RNE
  return (unsigned short)(x >> 16);
}
// packed edge: (src << 15) | (fp16(weight) >> 1)   [weight >= 0 so sign bit = 0]
__device__ inline unsigned int pack_edge(int src, float w) {
  unsigned short hb = __half_as_ushort(__float2half_rn(w));
  return ((unsigned int)src << 15) | ((unsigned int)hb >> 1);
}
__device__ inline void unpack_edge(unsigned int p, int& src, float& w) {
  src = (int)(p >> 15);
  w = __half2float(__ushort_as_half((unsigned short)((p & 0x7fffu) << 1)));
}

// ---------------- weight prepack: W[HOUT][K] f32 -> bf16 MFMA-B order ----------------
__global__ __launch_bounds__(256) void prepack_kernel(
    const float* __restrict__ Wrel0, const float* __restrict__ Wroot0,
    const float* __restrict__ WrelR, const float* __restrict__ WrootR,
    const float* __restrict__ Wr1, unsigned short* __restrict__ dst)
{
  int g = blockIdx.x * 256 + threadIdx.x;
  if (g >= 15360) return;
  const float* src; int H, K, r; unsigned short* out;
  if (g < 1024)       { src = Wrel0;  H = 128; K = 64;  r = g;        out = dst + r * 8; }
  else if (g < 2048)  { src = Wroot0; H = 128; K = 64;  r = g - 1024; out = dst + 8192 + r * 8; }
  else if (g < 8192)  { int m = g - 2048; int l = m / 2048; r = m % 2048;
                        src = WrelR + l * 16384;  H = 128; K = 128;
                        out = dst + 16384 + l * 16384 + r * 8; }
  else if (g < 14336) { int m = g - 8192; int l = m / 2048; r = m % 2048;
                        src = WrootR + l * 16384; H = 128; K = 128;
                        out = dst + 65536 + l * 16384 + r * 8; }
  else                { src = Wr1;    H = 64;  K = 128; r = g - 14336; out = dst + 114688 + r * 8; }
  int n = r % H, k8 = r / H;
  const float* s = src + (size_t)n * K + k8 * 8;
#pragma unroll
  for (int j = 0; j < 8; j++) out[j] = f2b(s[j]);
}

// ---------------- x f32 -> bf16 ----------------
__global__ __launch_bounds__(256) void cvt_x_kernel(
    const float* __restrict__ x, unsigned short* __restrict__ xb)
{
  int i = blockIdx.x * 256 + threadIdx.x;
  if (i * 4 >= NNODES * 64) return;
  float4 v = *(const float4*)(x + i * 4);
  ushort4 o;
  o.x = f2b(v.x); o.y = f2b(v.y); o.z = f2b(v.z); o.w = f2b(v.w);
  *(ushort4*)(xb + i * 4) = o;
}

// ---------------- bucketized CSR build ----------------
// Pass 1: per-chunk histogram of dst buckets. cnt[b * NCHUNK + c] (bucket-major).
__global__ __launch_bounds__(256) void bucket_count_kernel(
    const int* __restrict__ ei, int* __restrict__ cnt)
{
  __shared__ int hist[NBUCKET];
  for (int i = threadIdx.x; i < NBUCKET; i += 256) hist[i] = 0;
  __syncthreads();
  int base = blockIdx.x * CHUNK;
  for (int t = threadIdx.x; t < CHUNK; t += 256) {
    int e = base + t;
    if (e < NEDGES) atomicAdd(&hist[ei[NEDGES + e] >> 8], 1);
  }
  __syncthreads();
  for (int i = threadIdx.x; i < NBUCKET; i += 256)
    cnt[i * NCHUNK + blockIdx.x] = hist[i];
}

// Pass 2a: per-bucket-row exclusive scan (in-row offsets) + row total.
__global__ __launch_bounds__(512) void row_scan_kernel(
    int* __restrict__ cnt, int* __restrict__ rowsum)
{
  __shared__ int s[512];
  int b = blockIdx.x, t = threadIdx.x;
  int v = (t < NCHUNK) ? cnt[b * NCHUNK + t] : 0;
  s[t] = v;
  __syncthreads();
#pragma unroll
  for (int off = 1; off < 512; off <<= 1) {
    int u = (t >= off) ? s[t - off] : 0;
    __syncthreads();
    s[t] += u;
    __syncthreads();
  }
  if (t < NCHUNK) cnt[b * NCHUNK + t] = s[t] - v;
  if (t == 511) rowsum[b] = s[511];
}

// Pass 2b: exclusive scan of the 391 row totals -> rowbase[NBUCKET+1].
__global__ __launch_bounds__(512) void rowbase_scan_kernel(
    const int* __restrict__ rowsum, int* __restrict__ rowbase)
{
  __shared__ int s[512];
  int t = threadIdx.x;
  int v = (t < NBUCKET) ? rowsum[t] : 0;
  s[t] = v;
  __syncthreads();
#pragma unroll
  for (int off = 1; off < 512; off <<= 1) {
    int u = (t >= off) ? s[t - off] : 0;
    __syncthreads();
    s[t] += u;
    __syncthreads();
  }
  if (t < NBUCKET) rowbase[t] = s[t] - v;
  if (t == 511) rowbase[NBUCKET] = s[511];   // == NEDGES
}

// Pass 3: scatter edges into bucket-major record array (dst, packed_edge).
__global__ __launch_bounds__(256) void bucket_scatter_kernel(
    const int* __restrict__ ei, const float* __restrict__ ew,
    const int* __restrict__ cnt, const int* __restrict__ rowbase,
    uint2* __restrict__ rec)
{
  __shared__ int pos[NBUCKET];
  for (int i = threadIdx.x; i < NBUCKET; i += 256)
    pos[i] = rowbase[i] + cnt[i * NCHUNK + blockIdx.x];
  __syncthreads();
  int base = blockIdx.x * CHUNK;
  for (int t = threadIdx.x; t < CHUNK; t += 256) {
    int e = base + t;
    if (e < NEDGES) {
      int d = ei[NEDGES + e];
      int p = atomicAdd(&pos[d >> 8], 1);
      rec[p] = make_uint2((unsigned int)d, pack_edge(ei[e], ew[e]));
    }
  }
}

// Pass 4: one block per bucket. Local degree count + LDS scan writes row_ptr
// directly; then scatter epack into the bucket's contiguous 16KB window.
__global__ __launch_bounds__(256) void bucket_fill_kernel(
    const int* __restrict__ rowbase, const uint2* __restrict__ rec,
    unsigned int* __restrict__ epack, int* __restrict__ row_ptr)
{
  __shared__ int off[BK];
  __shared__ int s[256];
  int b = blockIdx.x, t = threadIdx.x;
  int start = rowbase[b];
  int end = rowbase[b + 1];
  int nbase = b * BK;
  off[t] = 0;
  __syncthreads();
  for (int i = start + t; i < end; i += 256)
    atomicAdd(&off[rec[i].x - nbase], 1);
  __syncthreads();
  int v = off[t];
  s[t] = v;
  __syncthreads();
#pragma unroll
  for (int o = 1; o < 256; o <<= 1) {
    int u = (t >= o) ? s[t - o] : 0;
    __syncthreads();
    s[t] += u;
    __syncthreads();
  }
  int ex = s[t] - v;
  int g = nbase + t;
  if (g <= NNODES) row_ptr[g] = start + ex;   // g==NNODES -> start+ex == NEDGES
  __syncthreads();
  off[t] = ex;
  __syncthreads();
  for (int i = start + t; i < end; i += 256) {
    uint2 r = rec[i];
    int lp = atomicAdd(&off[r.x - nbase], 1);
    epack[start + lp] = r.y;
  }
}

// ---------------- graph pointer (batch sorted) ----------------
__global__ __launch_bounds__(256) void gptr_kernel(
    const int* __restrict__ batch, int* __restrict__ gptr)
{
  int i = blockIdx.x * 256 + threadIdx.x;
  if (i >= NNODES) return;
  int b = batch[i];
  int bn = (i + 1 < NNODES) ? batch[i + 1] : NGRAPH;
  for (int g = b + 1; g <= bn; g++) gptr[g] = i + 1;
  if (i == 0) for (int g = 0; g <= b; g++) gptr[g] = 0;
}

// ---------------- split-K bf16 gather aggregation ----------------
// agg128: 2 waves per node; wave (node, half) processes edge window
// s + half*16 + {0..15} with stride 32 (quarter-split, 4-deep like R3's
// proven form). Partials combined through LDS. 2x wave count of R3 ->
// more loads in flight chip-wide (gather is latency-bound; R4/R6 showed
// delivered BW tracks resident wave count).
__global__ __launch_bounds__(256) void agg128_kernel(
    const int* __restrict__ row_ptr, const unsigned int* __restrict__ epack,
    const unsigned short* __restrict__ x, unsigned short* __restrict__ agg)
{
  __shared__ float part[4][128];
  const int wave = threadIdx.x >> 6, lane = threadIdx.x & 63;
  const int node = blockIdx.x * 2 + (wave >> 1);   // exact: 50000 blocks x 2 = NNODES
  const int half = wave & 1;
  const int q = lane >> 4, sl = lane & 15;
  int s = row_ptr[node], e = row_ptr[node + 1];
  float acc[8];
#pragma unroll
  for (int j = 0; j < 8; j++) acc[j] = 0.f;

  for (int i = s + half * 16 + q; i < e; i += 32) {
    unsigned int p0 = epack[i];
    unsigned int p1 = (i + 4  < e) ? epack[i + 4]  : 0u;
    unsigned int p2 = (i + 8  < e) ? epack[i + 8]  : 0u;
    unsigned int p3 = (i + 12 < e) ? epack[i + 12] : 0u;
    int s0, s1, s2, s3; float w0, w1, w2, w3;
    unpack_edge(p0, s0, w0);
    unpack_edge(p1, s1, w1);
    unpack_edge(p2, s2, w2);
    unpack_edge(p3, s3, w3);
    ushort8 r0 = *(const ushort8*)(x + (size_t)s0 * 128 + sl * 8);
    ushort8 r1 = *(const ushort8*)(x + (size_t)s1 * 128 + sl * 8);
    ushort8 r2 = *(const ushort8*)(x + (size_t)s2 * 128 + sl * 8);
    ushort8 r3 = *(const ushort8*)(x + (size_t)s3 * 128 + sl * 8);
#pragma unroll
    for (int j = 0; j < 8; j++)
      acc[j] += w0 * b2f(r0[j]) + w1 * b2f(r1[j]) +
                w2 * b2f(r2[j]) + w3 * b2f(r3[j]);
  }
#pragma unroll
  for (int j = 0; j < 8; j++) {
    acc[j] += __shfl_xor(acc[j], 16, 64);
    acc[j] += __shfl_xor(acc[j], 32, 64);
  }
  if (q == 0) {
#pragma unroll
    for (int j = 0; j < 8; j++) part[wave][sl * 8 + j] = acc[j];
  }
  __syncthreads();
  if (half == 0 && q == 0) {
    ushort8 o;
#pragma unroll
    for (int j = 0; j < 8; j++)
      o[j] = f2b(part[wave][sl * 8 + j] + part[wave + 1][sl * 8 + j]);
    *(ushort8*)(agg + (size_t)node * 128 + sl * 8) = o;
  }
}

// agg64: 2 waves per node, eighth-split, 2-deep, stride 32; LDS combine.
__global__ __launch_bounds__(256) void agg64_kernel(
    const int* __restrict__ row_ptr, const unsigned int* __restrict__ epack,
    const unsigned short* __restrict__ x, unsigned short* __restrict__ agg)
{
  __shared__ float part[4][64];
  const int wave = threadIdx.x >> 6, lane = threadIdx.x & 63;
  const int node = blockIdx.x * 2 + (wave >> 1);
  const int half = wave & 1;
  const int q = lane >> 3, sl = lane & 7;
  int s = row_ptr[node], e = row_ptr[node + 1];
  float acc[8];
#pragma unroll
  for (int j = 0; j < 8; j++) acc[j] = 0.f;

  for (int i = s + half * 16 + q; i < e; i += 32) {
    unsigned int p0 = epack[i];
    unsigned int p1 = (i + 8 < e) ? epack[i + 8] : 0u;
    int s0, s1; float w0, w1;
    unpack_edge(p0, s0, w0);
    unpack_edge(p1, s1, w1);
    ushort8 r0 = *(const ushort8*)(x + (size_t)s0 * 64 + sl * 8);
    ushort8 r1 = *(const ushort8*)(x + (size_t)s1 * 64 + sl * 8);
#pragma unroll
    for (int j = 0; j < 8; j++)
      acc[j] += w0 * b2f(r0[j]) + w1 * b2f(r1[j]);
  }
#pragma unroll
  for (int j = 0; j < 8; j++) {
    acc[j] += __shfl_xor(acc[j], 8, 64);
    acc[j] += __shfl_xor(acc[j], 16, 64);
    acc[j] += __shfl_xor(acc[j], 32, 64);
  }
  if (q == 0) {
#pragma unroll
    for (int j = 0; j < 8; j++) part[wave][sl * 8 + j] = acc[j];
  }
  __syncthreads();
  if (half == 0 && q == 0) {
    ushort8 o;
#pragma unroll
    for (int j = 0; j < 8; j++)
      o[j] = f2b(part[wave][sl * 8 + j] + part[wave + 1][sl * 8 + j]);
    *(ushort8*)(agg + (size_t)node * 64 + sl * 8) = o;
  }
}

// ---------------- LDS-free MFMA bf16 GEMM (GraphConv layers) ----------------
template <int KDIM, int HOUT, int MT, bool DUAL, bool RELU>
__global__ __launch_bounds__(256) void mfma_gemm(
    const unsigned short* __restrict__ A1, const unsigned short* __restrict__ W1,
    const unsigned short* __restrict__ A2, const unsigned short* __restrict__ W2,
    const float* __restrict__ bias, unsigned short* __restrict__ out)
{
  constexpr int NT2 = HOUT / 16;
  constexpr int KC = KDIM / 32;
  const int wave = threadIdx.x >> 6, lane = threadIdx.x & 63;
  const int quad = lane >> 4, l16 = lane & 15;
  const int n0 = (blockIdx.x * 4 + wave) * (MT * 16);

  f32x4 acc[MT][NT2];
#pragma unroll
  for (int m = 0; m < MT; m++)
#pragma unroll
    for (int t = 0; t < NT2; t++) acc[m][t] = (f32x4){0.f, 0.f, 0.f, 0.f};

  int nodes[MT];
#pragma unroll
  for (int m = 0; m < MT; m++) {
    int nd = n0 + m * 16 + l16;
    nodes[m] = nd < NNODES ? nd : NNODES - 1;
  }

#pragma unroll
  for (int c = 0; c < KC; c++) {
    short8 bfr[NT2];
#pragma unroll
    for (int t = 0; t < NT2; t++)
      bfr[t] = *(const short8*)(W1 + ((size_t)(c * 4 + quad) * HOUT + t * 16 + l16) * 8);
#pragma unroll
    for (int m = 0; m < MT; m++) {
      short8 af = *(const short8*)(A1 + (size_t)nodes[m] * KDIM + c * 32 + quad * 8);
#pragma unroll
      for (int t = 0; t < NT2; t++)
        acc[m][t] = __builtin_amdgcn_mfma_f32_16x16x32_bf16(af, bfr[t], acc[m][t], 0, 0, 0);
    }
    if (DUAL) {
#pragma unroll
      for (int t = 0; t < NT2; t++)
        bfr[t] = *(const short8*)(W2 + ((size_t)(c * 4 + quad) * HOUT + t * 16 + l16) * 8);
#pragma unroll
      for (int m = 0; m < MT; m++) {
        short8 af = *(const short8*)(A2 + (size_t)nodes[m] * KDIM + c * 32 + quad * 8);
#pragma unroll
        for (int t = 0; t < NT2; t++)
          acc[m][t] = __builtin_amdgcn_mfma_f32_16x16x32_bf16(af, bfr[t], acc[m][t], 0, 0, 0);
      }
    }
  }

#pragma unroll
  for (int m = 0; m < MT; m++) {
    int rowbase = n0 + m * 16 + quad * 4;
#pragma unroll
    for (int t = 0; t < NT2; t++) {
      float b = bias[t * 16 + l16];
#pragma unroll
      for (int r = 0; r < 4; r++) {
        int nd = rowbase + r;
        if (nd < NNODES) {
          float v = acc[m][t][r] + b;
          if (RELU) v = fmaxf(v, 0.f);
          out[(size_t)nd * HOUT + t * 16 + l16] = f2b(v);
        }
      }
    }
  }
}

// ---------------- fused readout: GEMM(128->64) + ReLU + dot(Wr2) + segment-sum ----------------
__global__ __launch_bounds__(256) void readout_fused_kernel(
    const unsigned short* __restrict__ A1, const unsigned short* __restrict__ W1,
    const float* __restrict__ br1, const float* __restrict__ Wr2,
    const int* __restrict__ batch, float* __restrict__ gnum)
{
  constexpr int NT2 = 4, KC = 4, MT = 4;
  const int wave = threadIdx.x >> 6, lane = threadIdx.x & 63;
  const int quad = lane >> 4, l16 = lane & 15;
  const int n0 = (blockIdx.x * 4 + wave) * (MT * 16);

  f32x4 acc[MT][NT2];
#pragma unroll
  for (int m = 0; m < MT; m++)
#pragma unroll
    for (int t = 0; t < NT2; t++) acc[m][t] = (f32x4){0.f, 0.f, 0.f, 0.f};

  int nodes[MT];
#pragma unroll
  for (int m = 0; m < MT; m++) {
    int nd = n0 + m * 16 + l16;
    nodes[m] = nd < NNODES ? nd : NNODES - 1;
  }

#pragma unroll
  for (int c = 0; c < KC; c++) {
    short8 bfr[NT2];
#pragma unroll
    for (int t = 0; t < NT2; t++)
      bfr[t] = *(const short8*)(W1 + ((size_t)(c * 4 + quad) * 64 + t * 16 + l16) * 8);
#pragma unroll
    for (int m = 0; m < MT; m++) {
      short8 af = *(const short8*)(A1 + (size_t)nodes[m] * 128 + c * 32 + quad * 8);
#pragma unroll
      for (int t = 0; t < NT2; t++)
        acc[m][t] = __builtin_amdgcn_mfma_f32_16x16x32_bf16(af, bfr[t], acc[m][t], 0, 0, 0);
    }
  }

  float bv[NT2], wv[NT2];
#pragma unroll
  for (int t = 0; t < NT2; t++) {
    bv[t] = br1[t * 16 + l16];
    wv[t] = Wr2[t * 16 + l16];
  }
#pragma unroll
  for (int m = 0; m < MT; m++) {
    int rowbase = n0 + m * 16 + quad * 4;
#pragma unroll
    for (int r = 0; r < 4; r++) {
      float p = 0.f;
#pragma unroll
      for (int t = 0; t < NT2; t++)
        p += fmaxf(acc[m][t][r] + bv[t], 0.f) * wv[t];
      p += __shfl_xor(p, 1, 64);
      p += __shfl_xor(p, 2, 64);
      p += __shfl_xor(p, 4, 64);
      p += __shfl_xor(p, 8, 64);
      int nd = rowbase + r;
      if (l16 == 0 && nd < NNODES)
        atomicAdd(&gnum[batch[nd]], p);
    }
  }
}

__global__ __launch_bounds__(256) void finalize_kernel(
    const float* __restrict__ gnum, const int* __restrict__ gptr,
    const float* __restrict__ br2, float* __restrict__ out)
{
  int g = blockIdx.x * 256 + threadIdx.x;
  if (g >= NGRAPH) return;
  float cnt = (float)(gptr[g + 1] - gptr[g]);
  out[g] = (gnum[g] + cnt * br2[0]) / fmaxf(cnt, 1.f);
}

// ---------------- launch ----------------
extern "C" void kernel_launch(void* const* d_in, const int* in_sizes, int n_in,
                              void* d_out, int out_size, void* d_ws, size_t ws_size,
                              hipStream_t stream)
{
  const float* x      = (const float*)d_in[0];
  const int*   ei     = (const int*)d_in[1];
  const float* ew     = (const float*)d_in[2];
  const int*   batch  = (const int*)d_in[3];
  const float* Wroot0 = (const float*)d_in[4];
  const float* Wrel0  = (const float*)d_in[5];
  const float* b0     = (const float*)d_in[6];
  const float* WrootR = (const float*)d_in[7];
  const float* WrelR  = (const float*)d_in[8];
  const float* bR     = (const float*)d_in[9];
  const float* Wr1    = (const float*)d_in[10];
  const float* br1    = (const float*)d_in[11];
  const float* Wr2    = (const float*)d_in[12];
  const float* br2    = (const float*)d_in[13];

  char* ws = (char*)d_ws;
  unsigned short* wp   = (unsigned short*)ws;                 // 122880 bf16, pad to 131072
  unsigned short* xb   = wp + 131072;                         // N*64 bf16
  unsigned short* agg0 = xb + (size_t)NNODES * 64;            // N*64 bf16 (layer-0 agg)
  unsigned short* bufA = agg0 + (size_t)NNODES * 64;          // N*128 bf16
  unsigned short* bufB = bufA + (size_t)NNODES * 128;         // N*128 bf16
  unsigned short* hbuf = bufB + (size_t)NNODES * 128;         // reused: gnum
  int*  cnt      = (int*)(hbuf + (size_t)NNODES * 64);        // NBE ints (~600KB)
  int*  rowsum   = cnt + ((NBE + 63) & ~63);
  int*  rowbase  = rowsum + NBUCKET + 1;
  int*  row_ptr  = rowbase + NBUCKET + 1;
  int*  gptr     = row_ptr + NNODES + 2;
  unsigned int* epack = (unsigned int*)(gptr + NGRAPH + 2);   // E uint = 6.4MB
  // rec aliases bufA (12.8MB <= 25.6MB); bufA first written by layer-1 agg128,
  // long after bucket_fill_kernel has consumed rec.
  uint2* rec = (uint2*)bufA;
  float* gnum = (float*)hbuf;

  prepack_kernel<<<60, 256, 0, stream>>>(Wrel0, Wroot0, WrelR, WrootR, Wr1, wp);
  cvt_x_kernel<<<(NNODES * 64 / 4 + 255) / 256, 256, 0, stream>>>(x, xb);
  hipMemsetAsync(gnum, 0, NGRAPH * sizeof(float), stream);

  const unsigned short* pWrel0  = wp;
  const unsigned short* pWroot0 = wp + 8192;
  const unsigned short* pWrelR  = wp + 16384;
  const unsigned short* pWrootR = wp + 65536;
  const unsigned short* pWr1    = wp + 114688;

  // bucketized CSR build (by dst) + graph ptr
  bucket_count_kernel<<<NCHUNK, 256, 0, stream>>>(ei, cnt);
  row_scan_kernel<<<NBUCKET, 512, 0, stream>>>(cnt, rowsum);
  rowbase_scan_kernel<<<1, 512, 0, stream>>>(rowsum, rowbase);
  bucket_scatter_kernel<<<NCHUNK, 256, 0, stream>>>(ei, ew, cnt, rowbase, rec);
  bucket_fill_kernel<<<NBUCKET, 256, 0, stream>>>(rowbase, rec, epack, row_ptr);
  gptr_kernel<<<(NNODES + 255) / 256, 256, 0, stream>>>(batch, gptr);

  // layer 0: 64 -> 128   (NNODES/2 = 50000 blocks, 2 nodes per block)
  agg64_kernel<<<NNODES / 2, 256, 0, stream>>>(row_ptr, epack, xb, agg0);
  mfma_gemm<64, 128, 2, true, false><<<(NNODES + 127) / 128, 256, 0, stream>>>(
      agg0, pWrel0, xb, pWroot0, b0, bufB);

  // layers 1..3: 128 -> 128
  unsigned short* bufs[2] = { bufB, bufA };
  for (int l = 0; l < 3; l++) {
    unsigned short* in  = bufs[l & 1];
    unsigned short* agg = bufs[(l & 1) ^ 1];
    agg128_kernel<<<NNODES / 2, 256, 0, stream>>>(row_ptr, epack, in, agg);
    mfma_gemm<128, 128, 2, true, false><<<(NNODES + 127) / 128, 256, 0, stream>>>(
        agg, pWrelR + l * 16384, in, pWrootR + l * 16384, bR + l * 128, agg);
  }
  // y3 in bufA

  // fused readout
  readout_fused_kernel<<<(NNODES + 255) / 256, 256, 0, stream>>>(
      bufA, pWr1, br1, Wr2, batch, gnum);
  finalize_kernel<<<(NGRAPH + 255) / 256, 256, 0, stream>>>(gnum, gptr, br2, (float*)d_out);
}

// Round 8
// 526.181 us; speedup vs baseline: 1.1195x; 1.1195x over previous
//
#include <hip/hip_runtime.h>
#include <hip/hip_fp16.h>
#include <cstdint>
#include <cstddef>

#define NNODES 100000
#define NEDGES 1600000
#define NGRAPH 1024

// bucketized CSR build
#define BK 256                             // nodes per bucket (dst >> 8)
#define NBUCKET 391                        // ceil(NNODES / BK)
#define CHUNK 4096
#define NCHUNK 391                         // ceil(NEDGES / CHUNK)
#define NBE (NBUCKET * NCHUNK)             // 152881 count-matrix entries

typedef __attribute__((ext_vector_type(8))) short short8;
typedef __attribute__((ext_vector_type(8))) unsigned short ushort8;
typedef __attribute__((ext_vector_type(4))) float f32x4;

__device__ inline float b2f(unsigned short u) {
  return __uint_as_float(((unsigned int)u) << 16);
}
__device__ inline unsigned short f2b(float f) {
  unsigned int x = __float_as_uint(f);
  x += 0x7fffu + ((x >> 16) & 1u);          // RNE
  return (unsigned short)(x >> 16);
}
// packed edge: (src << 15) | (fp16(weight) >> 1)   [weight >= 0 so sign bit = 0]
__device__ inline unsigned int pack_edge(int src, float w) {
  unsigned short hb = __half_as_ushort(__float2half_rn(w));
  return ((unsigned int)src << 15) | ((unsigned int)hb >> 1);
}
__device__ inline void unpack_edge(unsigned int p, int& src, float& w) {
  src = (int)(p >> 15);
  w = __half2float(__ushort_as_half((unsigned short)((p & 0x7fffu) << 1)));
}

// ---------------- weight prepack: W[HOUT][K] f32 -> bf16 MFMA-B order ----------------
__global__ __launch_bounds__(256) void prepack_kernel(
    const float* __restrict__ Wrel0, const float* __restrict__ Wroot0,
    const float* __restrict__ WrelR, const float* __restrict__ WrootR,
    const float* __restrict__ Wr1, unsigned short* __restrict__ dst)
{
  int g = blockIdx.x * 256 + threadIdx.x;
  if (g >= 15360) return;
  const float* src; int H, K, r; unsigned short* out;
  if (g < 1024)       { src = Wrel0;  H = 128; K = 64;  r = g;        out = dst + r * 8; }
  else if (g < 2048)  { src = Wroot0; H = 128; K = 64;  r = g - 1024; out = dst + 8192 + r * 8; }
  else if (g < 8192)  { int m = g - 2048; int l = m / 2048; r = m % 2048;
                        src = WrelR + l * 16384;  H = 128; K = 128;
                        out = dst + 16384 + l * 16384 + r * 8; }
  else if (g < 14336) { int m = g - 8192; int l = m / 2048; r = m % 2048;
                        src = WrootR + l * 16384; H = 128; K = 128;
                        out = dst + 65536 + l * 16384 + r * 8; }
  else                { src = Wr1;    H = 64;  K = 128; r = g - 14336; out = dst + 114688 + r * 8; }
  int n = r % H, k8 = r / H;
  const float* s = src + (size_t)n * K + k8 * 8;
#pragma unroll
  for (int j = 0; j < 8; j++) out[j] = f2b(s[j]);
}

// ---------------- x f32 -> bf16 ----------------
__global__ __launch_bounds__(256) void cvt_x_kernel(
    const float* __restrict__ x, unsigned short* __restrict__ xb)
{
  int i = blockIdx.x * 256 + threadIdx.x;
  if (i * 4 >= NNODES * 64) return;
  float4 v = *(const float4*)(x + i * 4);
  ushort4 o;
  o.x = f2b(v.x); o.y = f2b(v.y); o.z = f2b(v.z); o.w = f2b(v.w);
  *(ushort4*)(xb + i * 4) = o;
}

// ---------------- bucketized CSR build ----------------
// Pass 1: per-chunk histogram of dst buckets. cnt[b * NCHUNK + c] (bucket-major).
__global__ __launch_bounds__(256) void bucket_count_kernel(
    const int* __restrict__ ei, int* __restrict__ cnt)
{
  __shared__ int hist[NBUCKET];
  for (int i = threadIdx.x; i < NBUCKET; i += 256) hist[i] = 0;
  __syncthreads();
  int base = blockIdx.x * CHUNK;
  for (int t = threadIdx.x; t < CHUNK; t += 256) {
    int e = base + t;
    if (e < NEDGES) atomicAdd(&hist[ei[NEDGES + e] >> 8], 1);
  }
  __syncthreads();
  for (int i = threadIdx.x; i < NBUCKET; i += 256)
    cnt[i * NCHUNK + blockIdx.x] = hist[i];
}

// Pass 2a: per-bucket-row exclusive scan (in-row offsets) + row total.
__global__ __launch_bounds__(512) void row_scan_kernel(
    int* __restrict__ cnt, int* __restrict__ rowsum)
{
  __shared__ int s[512];
  int b = blockIdx.x, t = threadIdx.x;
  int v = (t < NCHUNK) ? cnt[b * NCHUNK + t] : 0;
  s[t] = v;
  __syncthreads();
#pragma unroll
  for (int off = 1; off < 512; off <<= 1) {
    int u = (t >= off) ? s[t - off] : 0;
    __syncthreads();
    s[t] += u;
    __syncthreads();
  }
  if (t < NCHUNK) cnt[b * NCHUNK + t] = s[t] - v;
  if (t == 511) rowsum[b] = s[511];
}

// Pass 2b: exclusive scan of the 391 row totals -> rowbase[NBUCKET+1].
__global__ __launch_bounds__(512) void rowbase_scan_kernel(
    const int* __restrict__ rowsum, int* __restrict__ rowbase)
{
  __shared__ int s[512];
  int t = threadIdx.x;
  int v = (t < NBUCKET) ? rowsum[t] : 0;
  s[t] = v;
  __syncthreads();
#pragma unroll
  for (int off = 1; off < 512; off <<= 1) {
    int u = (t >= off) ? s[t - off] : 0;
    __syncthreads();
    s[t] += u;
    __syncthreads();
  }
  if (t < NBUCKET) rowbase[t] = s[t] - v;
  if (t == 511) rowbase[NBUCKET] = s[511];   // == NEDGES
}

// Pass 3: scatter edges into bucket-major record array (dst, packed_edge).
__global__ __launch_bounds__(256) void bucket_scatter_kernel(
    const int* __restrict__ ei, const float* __restrict__ ew,
    const int* __restrict__ cnt, const int* __restrict__ rowbase,
    uint2* __restrict__ rec)
{
  __shared__ int pos[NBUCKET];
  for (int i = threadIdx.x; i < NBUCKET; i += 256)
    pos[i] = rowbase[i] + cnt[i * NCHUNK + blockIdx.x];
  __syncthreads();
  int base = blockIdx.x * CHUNK;
  for (int t = threadIdx.x; t < CHUNK; t += 256) {
    int e = base + t;
    if (e < NEDGES) {
      int d = ei[NEDGES + e];
      int p = atomicAdd(&pos[d >> 8], 1);
      rec[p] = make_uint2((unsigned int)d, pack_edge(ei[e], ew[e]));
    }
  }
}

// Pass 4: one block per bucket. Local degree count + LDS scan writes row_ptr
// directly; then scatter epack into the bucket's contiguous 16KB window.
__global__ __launch_bounds__(256) void bucket_fill_kernel(
    const int* __restrict__ rowbase, const uint2* __restrict__ rec,
    unsigned int* __restrict__ epack, int* __restrict__ row_ptr)
{
  __shared__ int off[BK];
  __shared__ int s[256];
  int b = blockIdx.x, t = threadIdx.x;
  int start = rowbase[b];
  int end = rowbase[b + 1];
  int nbase = b * BK;
  off[t] = 0;
  __syncthreads();
  for (int i = start + t; i < end; i += 256)
    atomicAdd(&off[rec[i].x - nbase], 1);
  __syncthreads();
  int v = off[t];
  s[t] = v;
  __syncthreads();
#pragma unroll
  for (int o = 1; o < 256; o <<= 1) {
    int u = (t >= o) ? s[t - o] : 0;
    __syncthreads();
    s[t] += u;
    __syncthreads();
  }
  int ex = s[t] - v;
  int g = nbase + t;
  if (g <= NNODES) row_ptr[g] = start + ex;   // g==NNODES -> start+ex == NEDGES
  __syncthreads();
  off[t] = ex;
  __syncthreads();
  for (int i = start + t; i < end; i += 256) {
    uint2 r = rec[i];
    int lp = atomicAdd(&off[r.x - nbase], 1);
    epack[start + lp] = r.y;
  }
}

// ---------------- graph pointer (batch sorted) ----------------
__global__ __launch_bounds__(256) void gptr_kernel(
    const int* __restrict__ batch, int* __restrict__ gptr)
{
  int i = blockIdx.x * 256 + threadIdx.x;
  if (i >= NNODES) return;
  int b = batch[i];
  int bn = (i + 1 < NNODES) ? batch[i + 1] : NGRAPH;
  for (int g = b + 1; g <= bn; g++) gptr[g] = i + 1;
  if (i == 0) for (int g = 0; g <= b; g++) gptr[g] = 0;
}

// ---------------- bf16 gather aggregation ----------------
// agg128: 1 wave/node (R3's proven form), quarter-split, 8-deep: two 4-groups
// per loop iteration (stride 32) -> 32 rows in flight per wave at UNCHANGED
// wave count (100k). Tests the latency-hiding axis cleanly vs R3's 4-deep.
__global__ __launch_bounds__(256) void agg128_kernel(
    const int* __restrict__ row_ptr, const unsigned int* __restrict__ epack,
    const unsigned short* __restrict__ x, unsigned short* __restrict__ agg)
{
  int node = blockIdx.x * 4 + (threadIdx.x >> 6);
  int lane = threadIdx.x & 63;
  if (node >= NNODES) return;
  int q = lane >> 4, sl = lane & 15;
  int s = row_ptr[node], e = row_ptr[node + 1];
  float acc[8];
#pragma unroll
  for (int j = 0; j < 8; j++) acc[j] = 0.f;

  for (int i = s + q; i < e; i += 32) {
    unsigned int p0 = epack[i];
    unsigned int p1 = (i + 4  < e) ? epack[i + 4]  : 0u;
    unsigned int p2 = (i + 8  < e) ? epack[i + 8]  : 0u;
    unsigned int p3 = (i + 12 < e) ? epack[i + 12] : 0u;
    unsigned int p4 = (i + 16 < e) ? epack[i + 16] : 0u;
    unsigned int p5 = (i + 20 < e) ? epack[i + 20] : 0u;
    unsigned int p6 = (i + 24 < e) ? epack[i + 24] : 0u;
    unsigned int p7 = (i + 28 < e) ? epack[i + 28] : 0u;
    int s0, s1, s2, s3, s4, s5, s6, s7;
    float w0, w1, w2, w3, w4, w5, w6, w7;
    unpack_edge(p0, s0, w0); unpack_edge(p1, s1, w1);
    unpack_edge(p2, s2, w2); unpack_edge(p3, s3, w3);
    unpack_edge(p4, s4, w4); unpack_edge(p5, s5, w5);
    unpack_edge(p6, s6, w6); unpack_edge(p7, s7, w7);
    ushort8 r0 = *(const ushort8*)(x + (size_t)s0 * 128 + sl * 8);
    ushort8 r1 = *(const ushort8*)(x + (size_t)s1 * 128 + sl * 8);
    ushort8 r2 = *(const ushort8*)(x + (size_t)s2 * 128 + sl * 8);
    ushort8 r3 = *(const ushort8*)(x + (size_t)s3 * 128 + sl * 8);
    ushort8 r4 = *(const ushort8*)(x + (size_t)s4 * 128 + sl * 8);
    ushort8 r5 = *(const ushort8*)(x + (size_t)s5 * 128 + sl * 8);
    ushort8 r6 = *(const ushort8*)(x + (size_t)s6 * 128 + sl * 8);
    ushort8 r7 = *(const ushort8*)(x + (size_t)s7 * 128 + sl * 8);
#pragma unroll
    for (int j = 0; j < 8; j++)
      acc[j] += w0 * b2f(r0[j]) + w1 * b2f(r1[j]) +
                w2 * b2f(r2[j]) + w3 * b2f(r3[j]) +
                w4 * b2f(r4[j]) + w5 * b2f(r5[j]) +
                w6 * b2f(r6[j]) + w7 * b2f(r7[j]);
  }
#pragma unroll
  for (int j = 0; j < 8; j++) {
    acc[j] += __shfl_xor(acc[j], 16, 64);
    acc[j] += __shfl_xor(acc[j], 32, 64);
  }
  if (q == 0) {
    ushort8 o;
#pragma unroll
    for (int j = 0; j < 8; j++) o[j] = f2b(acc[j]);
    *(ushort8*)(agg + (size_t)node * 128 + sl * 8) = o;
  }
}

// agg64: 1 wave/node, eighth-split, 4-deep (two 2-groups, stride 32).
__global__ __launch_bounds__(256) void agg64_kernel(
    const int* __restrict__ row_ptr, const unsigned int* __restrict__ epack,
    const unsigned short* __restrict__ x, unsigned short* __restrict__ agg)
{
  int node = blockIdx.x * 4 + (threadIdx.x >> 6);
  int lane = threadIdx.x & 63;
  if (node >= NNODES) return;
  int q = lane >> 3, sl = lane & 7;
  int s = row_ptr[node], e = row_ptr[node + 1];
  float acc[8];
#pragma unroll
  for (int j = 0; j < 8; j++) acc[j] = 0.f;

  for (int i = s + q; i < e; i += 32) {
    unsigned int p0 = epack[i];
    unsigned int p1 = (i + 8  < e) ? epack[i + 8]  : 0u;
    unsigned int p2 = (i + 16 < e) ? epack[i + 16] : 0u;
    unsigned int p3 = (i + 24 < e) ? epack[i + 24] : 0u;
    int s0, s1, s2, s3; float w0, w1, w2, w3;
    unpack_edge(p0, s0, w0); unpack_edge(p1, s1, w1);
    unpack_edge(p2, s2, w2); unpack_edge(p3, s3, w3);
    ushort8 r0 = *(const ushort8*)(x + (size_t)s0 * 64 + sl * 8);
    ushort8 r1 = *(const ushort8*)(x + (size_t)s1 * 64 + sl * 8);
    ushort8 r2 = *(const ushort8*)(x + (size_t)s2 * 64 + sl * 8);
    ushort8 r3 = *(const ushort8*)(x + (size_t)s3 * 64 + sl * 8);
#pragma unroll
    for (int j = 0; j < 8; j++)
      acc[j] += w0 * b2f(r0[j]) + w1 * b2f(r1[j]) +
                w2 * b2f(r2[j]) + w3 * b2f(r3[j]);
  }
#pragma unroll
  for (int j = 0; j < 8; j++) {
    acc[j] += __shfl_xor(acc[j], 8, 64);
    acc[j] += __shfl_xor(acc[j], 16, 64);
    acc[j] += __shfl_xor(acc[j], 32, 64);
  }
  if (q == 0) {
    ushort8 o;
#pragma unroll
    for (int j = 0; j < 8; j++) o[j] = f2b(acc[j]);
    *(ushort8*)(agg + (size_t)node * 64 + sl * 8) = o;
  }
}

// ---------------- LDS-free MFMA bf16 GEMM (GraphConv layers) ----------------
template <int KDIM, int HOUT, int MT, bool DUAL, bool RELU>
__global__ __launch_bounds__(256) void mfma_gemm(
    const unsigned short* __restrict__ A1, const unsigned short* __restrict__ W1,
    const unsigned short* __restrict__ A2, const unsigned short* __restrict__ W2,
    const float* __restrict__ bias, unsigned short* __restrict__ out)
{
  constexpr int NT2 = HOUT / 16;
  constexpr int KC = KDIM / 32;
  const int wave = threadIdx.x >> 6, lane = threadIdx.x & 63;
  const int quad = lane >> 4, l16 = lane & 15;
  const int n0 = (blockIdx.x * 4 + wave) * (MT * 16);

  f32x4 acc[MT][NT2];
#pragma unroll
  for (int m = 0; m < MT; m++)
#pragma unroll
    for (int t = 0; t < NT2; t++) acc[m][t] = (f32x4){0.f, 0.f, 0.f, 0.f};

  int nodes[MT];
#pragma unroll
  for (int m = 0; m < MT; m++) {
    int nd = n0 + m * 16 + l16;
    nodes[m] = nd < NNODES ? nd : NNODES - 1;
  }

#pragma unroll
  for (int c = 0; c < KC; c++) {
    short8 bfr[NT2];
#pragma unroll
    for (int t = 0; t < NT2; t++)
      bfr[t] = *(const short8*)(W1 + ((size_t)(c * 4 + quad) * HOUT + t * 16 + l16) * 8);
#pragma unroll
    for (int m = 0; m < MT; m++) {
      short8 af = *(const short8*)(A1 + (size_t)nodes[m] * KDIM + c * 32 + quad * 8);
#pragma unroll
      for (int t = 0; t < NT2; t++)
        acc[m][t] = __builtin_amdgcn_mfma_f32_16x16x32_bf16(af, bfr[t], acc[m][t], 0, 0, 0);
    }
    if (DUAL) {
#pragma unroll
      for (int t = 0; t < NT2; t++)
        bfr[t] = *(const short8*)(W2 + ((size_t)(c * 4 + quad) * HOUT + t * 16 + l16) * 8);
#pragma unroll
      for (int m = 0; m < MT; m++) {
        short8 af = *(const short8*)(A2 + (size_t)nodes[m] * KDIM + c * 32 + quad * 8);
#pragma unroll
        for (int t = 0; t < NT2; t++)
          acc[m][t] = __builtin_amdgcn_mfma_f32_16x16x32_bf16(af, bfr[t], acc[m][t], 0, 0, 0);
      }
    }
  }

#pragma unroll
  for (int m = 0; m < MT; m++) {
    int rowbase = n0 + m * 16 + quad * 4;
#pragma unroll
    for (int t = 0; t < NT2; t++) {
      float b = bias[t * 16 + l16];
#pragma unroll
      for (int r = 0; r < 4; r++) {
        int nd = rowbase + r;
        if (nd < NNODES) {
          float v = acc[m][t][r] + b;
          if (RELU) v = fmaxf(v, 0.f);
          out[(size_t)nd * HOUT + t * 16 + l16] = f2b(v);
        }
      }
    }
  }
}

// ---------------- fused readout: GEMM(128->64) + ReLU + dot(Wr2) + segment-sum ----------------
__global__ __launch_bounds__(256) void readout_fused_kernel(
    const unsigned short* __restrict__ A1, const unsigned short* __restrict__ W1,
    const float* __restrict__ br1, const float* __restrict__ Wr2,
    const int* __restrict__ batch, float* __restrict__ gnum)
{
  constexpr int NT2 = 4, KC = 4, MT = 4;
  const int wave = threadIdx.x >> 6, lane = threadIdx.x & 63;
  const int quad = lane >> 4, l16 = lane & 15;
  const int n0 = (blockIdx.x * 4 + wave) * (MT * 16);

  f32x4 acc[MT][NT2];
#pragma unroll
  for (int m = 0; m < MT; m++)
#pragma unroll
    for (int t = 0; t < NT2; t++) acc[m][t] = (f32x4){0.f, 0.f, 0.f, 0.f};

  int nodes[MT];
#pragma unroll
  for (int m = 0; m < MT; m++) {
    int nd = n0 + m * 16 + l16;
    nodes[m] = nd < NNODES ? nd : NNODES - 1;
  }

#pragma unroll
  for (int c = 0; c < KC; c++) {
    short8 bfr[NT2];
#pragma unroll
    for (int t = 0; t < NT2; t++)
      bfr[t] = *(const short8*)(W1 + ((size_t)(c * 4 + quad) * 64 + t * 16 + l16) * 8);
#pragma unroll
    for (int m = 0; m < MT; m++) {
      short8 af = *(const short8*)(A1 + (size_t)nodes[m] * 128 + c * 32 + quad * 8);
#pragma unroll
      for (int t = 0; t < NT2; t++)
        acc[m][t] = __builtin_amdgcn_mfma_f32_16x16x32_bf16(af, bfr[t], acc[m][t], 0, 0, 0);
    }
  }

  float bv[NT2], wv[NT2];
#pragma unroll
  for (int t = 0; t < NT2; t++) {
    bv[t] = br1[t * 16 + l16];
    wv[t] = Wr2[t * 16 + l16];
  }
#pragma unroll
  for (int m = 0; m < MT; m++) {
    int rowbase = n0 + m * 16 + quad * 4;
#pragma unroll
    for (int r = 0; r < 4; r++) {
      float p = 0.f;
#pragma unroll
      for (int t = 0; t < NT2; t++)
        p += fmaxf(acc[m][t][r] + bv[t], 0.f) * wv[t];
      p += __shfl_xor(p, 1, 64);
      p += __shfl_xor(p, 2, 64);
      p += __shfl_xor(p, 4, 64);
      p += __shfl_xor(p, 8, 64);
      int nd = rowbase + r;
      if (l16 == 0 && nd < NNODES)
        atomicAdd(&gnum[batch[nd]], p);
    }
  }
}

__global__ __launch_bounds__(256) void finalize_kernel(
    const float* __restrict__ gnum, const int* __restrict__ gptr,
    const float* __restrict__ br2, float* __restrict__ out)
{
  int g = blockIdx.x * 256 + threadIdx.x;
  if (g >= NGRAPH) return;
  float cnt = (float)(gptr[g + 1] - gptr[g]);
  out[g] = (gnum[g] + cnt * br2[0]) / fmaxf(cnt, 1.f);
}

// ---------------- launch ----------------
extern "C" void kernel_launch(void* const* d_in, const int* in_sizes, int n_in,
                              void* d_out, int out_size, void* d_ws, size_t ws_size,
                              hipStream_t stream)
{
  const float* x      = (const float*)d_in[0];
  const int*   ei     = (const int*)d_in[1];
  const float* ew     = (const float*)d_in[2];
  const int*   batch  = (const int*)d_in[3];
  const float* Wroot0 = (const float*)d_in[4];
  const float* Wrel0  = (const float*)d_in[5];
  const float* b0     = (const float*)d_in[6];
  const float* WrootR = (const float*)d_in[7];
  const float* WrelR  = (const float*)d_in[8];
  const float* bR     = (const float*)d_in[9];
  const float* Wr1    = (const float*)d_in[10];
  const float* br1    = (const float*)d_in[11];
  const float* Wr2    = (const float*)d_in[12];
  const float* br2    = (const float*)d_in[13];

  char* ws = (char*)d_ws;
  unsigned short* wp   = (unsigned short*)ws;                 // 122880 bf16, pad to 131072
  unsigned short* xb   = wp + 131072;                         // N*64 bf16
  unsigned short* agg0 = xb + (size_t)NNODES * 64;            // N*64 bf16 (layer-0 agg)
  unsigned short* bufA = agg0 + (size_t)NNODES * 64;          // N*128 bf16
  unsigned short* bufB = bufA + (size_t)NNODES * 128;         // N*128 bf16
  unsigned short* hbuf = bufB + (size_t)NNODES * 128;         // reused: gnum
  int*  cnt      = (int*)(hbuf + (size_t)NNODES * 64);        // NBE ints (~600KB)
  int*  rowsum   = cnt + ((NBE + 63) & ~63);
  int*  rowbase  = rowsum + NBUCKET + 1;
  int*  row_ptr  = rowbase + NBUCKET + 1;
  int*  gptr     = row_ptr + NNODES + 2;
  unsigned int* epack = (unsigned int*)(gptr + NGRAPH + 2);   // E uint = 6.4MB
  // rec aliases bufA (12.8MB <= 25.6MB); bufA first written by layer-1 agg128,
  // long after bucket_fill_kernel has consumed rec.
  uint2* rec = (uint2*)bufA;
  float* gnum = (float*)hbuf;

  prepack_kernel<<<60, 256, 0, stream>>>(Wrel0, Wroot0, WrelR, WrootR, Wr1, wp);
  cvt_x_kernel<<<(NNODES * 64 / 4 + 255) / 256, 256, 0, stream>>>(x, xb);
  hipMemsetAsync(gnum, 0, NGRAPH * sizeof(float), stream);

  const unsigned short* pWrel0  = wp;
  const unsigned short* pWroot0 = wp + 8192;
  const unsigned short* pWrelR  = wp + 16384;
  const unsigned short* pWrootR = wp + 65536;
  const unsigned short* pWr1    = wp + 114688;

  // bucketized CSR build (by dst) + graph ptr
  bucket_count_kernel<<<NCHUNK, 256, 0, stream>>>(ei, cnt);
  row_scan_kernel<<<NBUCKET, 512, 0, stream>>>(cnt, rowsum);
  rowbase_scan_kernel<<<1, 512, 0, stream>>>(rowsum, rowbase);
  bucket_scatter_kernel<<<NCHUNK, 256, 0, stream>>>(ei, ew, cnt, rowbase, rec);
  bucket_fill_kernel<<<NBUCKET, 256, 0, stream>>>(rowbase, rec, epack, row_ptr);
  gptr_kernel<<<(NNODES + 255) / 256, 256, 0, stream>>>(batch, gptr);

  const int NW = (NNODES + 63) / 64;   // 1563 blocks for MT=1 GEMMs

  // layer 0: 64 -> 128
  agg64_kernel<<<(NNODES + 3) / 4, 256, 0, stream>>>(row_ptr, epack, xb, agg0);
  mfma_gemm<64, 128, 1, true, false><<<NW, 256, 0, stream>>>(
      agg0, pWrel0, xb, pWroot0, b0, bufB);

  // layers 1..3: 128 -> 128
  unsigned short* bufs[2] = { bufB, bufA };
  for (int l = 0; l < 3; l++) {
    unsigned short* in  = bufs[l & 1];
    unsigned short* agg = bufs[(l & 1) ^ 1];
    agg128_kernel<<<(NNODES + 3) / 4, 256, 0, stream>>>(row_ptr, epack, in, agg);
    mfma_gemm<128, 128, 1, true, false><<<NW, 256, 0, stream>>>(
        agg, pWrelR + l * 16384, in, pWrootR + l * 16384, bR + l * 128, agg);
  }
  // y3 in bufA

  // fused readout
  readout_fused_kernel<<<(NNODES + 255) / 256, 256, 0, stream>>>(
      bufA, pWr1, br1, Wr2, batch, gnum);
  finalize_kernel<<<(NGRAPH + 255) / 256, 256, 0, stream>>>(gnum, gptr, br2, (float*)d_out);
}

// Round 9
// 523.955 us; speedup vs baseline: 1.1242x; 1.0042x over previous
//
#include <hip/hip_runtime.h>
#include <hip/hip_fp16.h>
#include <cstdint>
#include <cstddef>

#define NNODES 100000
#define NEDGES 1600000
#define NGRAPH 1024

// bucketized CSR build
#define BK 256                             // nodes per bucket (dst >> 8)
#define NBUCKET 391                        // ceil(NNODES / BK)
#define CHUNK 4096
#define NCHUNK 391                         // ceil(NEDGES / CHUNK)
#define NBE (NBUCKET * NCHUNK)             // 152881 count-matrix entries

// setup_kernel block ranges
#define SB_CVT 6250                        // NNODES*64/4/256
#define SB_PRE (SB_CVT + 60)
#define SB_GPTR (SB_PRE + 391)
#define SB_CNT (SB_GPTR + NCHUNK)
#define SB_TOTAL (SB_CNT + 1)

typedef __attribute__((ext_vector_type(8))) short short8;
typedef __attribute__((ext_vector_type(8))) unsigned short ushort8;
typedef __attribute__((ext_vector_type(4))) float f32x4;

__device__ inline float b2f(unsigned short u) {
  return __uint_as_float(((unsigned int)u) << 16);
}
__device__ inline unsigned short f2b(float f) {
  unsigned int x = __float_as_uint(f);
  x += 0x7fffu + ((x >> 16) & 1u);          // RNE
  return (unsigned short)(x >> 16);
}
// packed edge: (src << 15) | (fp16(weight) >> 1)   [weight >= 0 so sign bit = 0]
__device__ inline unsigned int pack_edge(int src, float w) {
  unsigned short hb = __half_as_ushort(__float2half_rn(w));
  return ((unsigned int)src << 15) | ((unsigned int)hb >> 1);
}
__device__ inline void unpack_edge(unsigned int p, int& src, float& w) {
  src = (int)(p >> 15);
  w = __half2float(__ushort_as_half((unsigned short)((p & 0x7fffu) << 1)));
}

// ---------------- fused setup: cvt_x | prepack | gptr | bucket_count | gnum-zero ----------------
// Each block takes exactly one uniform branch -> no divergence hazards.
__global__ __launch_bounds__(256) void setup_kernel(
    const float* __restrict__ x, unsigned short* __restrict__ xb,
    const float* __restrict__ Wrel0, const float* __restrict__ Wroot0,
    const float* __restrict__ WrelR, const float* __restrict__ WrootR,
    const float* __restrict__ Wr1, unsigned short* __restrict__ wp,
    const int* __restrict__ batch, int* __restrict__ gptr,
    const int* __restrict__ ei, int* __restrict__ cnt,
    float* __restrict__ gnum)
{
  __shared__ int hist[NBUCKET];
  int blk = blockIdx.x;
  if (blk < SB_CVT) {
    // x f32 -> bf16, 4 elems/thread
    int i = blk * 256 + threadIdx.x;
    float4 v = *(const float4*)(x + (size_t)i * 4);
    ushort4 o;
    o.x = f2b(v.x); o.y = f2b(v.y); o.z = f2b(v.z); o.w = f2b(v.w);
    *(ushort4*)(xb + (size_t)i * 4) = o;
  } else if (blk < SB_PRE) {
    // weight prepack: W[HOUT][K] f32 -> bf16 MFMA-B order
    int g = (blk - SB_CVT) * 256 + threadIdx.x;
    if (g >= 15360) return;
    const float* src; int H, K, r; unsigned short* out;
    if (g < 1024)       { src = Wrel0;  H = 128; K = 64;  r = g;        out = wp + r * 8; }
    else if (g < 2048)  { src = Wroot0; H = 128; K = 64;  r = g - 1024; out = wp + 8192 + r * 8; }
    else if (g < 8192)  { int m = g - 2048; int l = m / 2048; r = m % 2048;
                          src = WrelR + l * 16384;  H = 128; K = 128;
                          out = wp + 16384 + l * 16384 + r * 8; }
    else if (g < 14336) { int m = g - 8192; int l = m / 2048; r = m % 2048;
                          src = WrootR + l * 16384; H = 128; K = 128;
                          out = wp + 65536 + l * 16384 + r * 8; }
    else                { src = Wr1;    H = 64;  K = 128; r = g - 14336; out = wp + 114688 + r * 8; }
    int n = r % H, k8 = r / H;
    const float* s = src + (size_t)n * K + k8 * 8;
#pragma unroll
    for (int j = 0; j < 8; j++) out[j] = f2b(s[j]);
  } else if (blk < SB_GPTR) {
    // graph pointer (batch sorted)
    int i = (blk - SB_PRE) * 256 + threadIdx.x;
    if (i >= NNODES) return;
    int b = batch[i];
    int bn = (i + 1 < NNODES) ? batch[i + 1] : NGRAPH;
    for (int g = b + 1; g <= bn; g++) gptr[g] = i + 1;
    if (i == 0) for (int g = 0; g <= b; g++) gptr[g] = 0;
  } else if (blk < SB_CNT) {
    // per-chunk histogram of dst buckets
    int chunk = blk - SB_GPTR;
    for (int i = threadIdx.x; i < NBUCKET; i += 256) hist[i] = 0;
    __syncthreads();
    int base = chunk * CHUNK;
    for (int t = threadIdx.x; t < CHUNK; t += 256) {
      int e = base + t;
      if (e < NEDGES) atomicAdd(&hist[ei[NEDGES + e] >> 8], 1);
    }
    __syncthreads();
    for (int i = threadIdx.x; i < NBUCKET; i += 256)
      cnt[i * NCHUNK + chunk] = hist[i];
  } else {
    // zero gnum[NGRAPH]
#pragma unroll
    for (int j = 0; j < 4; j++) gnum[threadIdx.x + j * 256] = 0.f;
  }
}

// ---------------- bucketized CSR build ----------------
// Pass 2a: per-bucket-row exclusive scan (in-row offsets) + row total.
__global__ __launch_bounds__(512) void row_scan_kernel(
    int* __restrict__ cnt, int* __restrict__ rowsum)
{
  __shared__ int s[512];
  int b = blockIdx.x, t = threadIdx.x;
  int v = (t < NCHUNK) ? cnt[b * NCHUNK + t] : 0;
  s[t] = v;
  __syncthreads();
#pragma unroll
  for (int off = 1; off < 512; off <<= 1) {
    int u = (t >= off) ? s[t - off] : 0;
    __syncthreads();
    s[t] += u;
    __syncthreads();
  }
  if (t < NCHUNK) cnt[b * NCHUNK + t] = s[t] - v;
  if (t == 511) rowsum[b] = s[511];
}

// Pass 2b: exclusive scan of the 391 row totals -> rowbase[NBUCKET+1].
__global__ __launch_bounds__(512) void rowbase_scan_kernel(
    const int* __restrict__ rowsum, int* __restrict__ rowbase)
{
  __shared__ int s[512];
  int t = threadIdx.x;
  int v = (t < NBUCKET) ? rowsum[t] : 0;
  s[t] = v;
  __syncthreads();
#pragma unroll
  for (int off = 1; off < 512; off <<= 1) {
    int u = (t >= off) ? s[t - off] : 0;
    __syncthreads();
    s[t] += u;
    __syncthreads();
  }
  if (t < NBUCKET) rowbase[t] = s[t] - v;
  if (t == 511) rowbase[NBUCKET] = s[511];   // == NEDGES
}

// Pass 3: scatter edges into bucket-major record array (dst, packed_edge).
__global__ __launch_bounds__(256) void bucket_scatter_kernel(
    const int* __restrict__ ei, const float* __restrict__ ew,
    const int* __restrict__ cnt, const int* __restrict__ rowbase,
    uint2* __restrict__ rec)
{
  __shared__ int pos[NBUCKET];
  for (int i = threadIdx.x; i < NBUCKET; i += 256)
    pos[i] = rowbase[i] + cnt[i * NCHUNK + blockIdx.x];
  __syncthreads();
  int base = blockIdx.x * CHUNK;
  for (int t = threadIdx.x; t < CHUNK; t += 256) {
    int e = base + t;
    if (e < NEDGES) {
      int d = ei[NEDGES + e];
      int p = atomicAdd(&pos[d >> 8], 1);
      rec[p] = make_uint2((unsigned int)d, pack_edge(ei[e], ew[e]));
    }
  }
}

// Pass 4: one block per bucket. Local degree count + LDS scan writes row_ptr
// directly; then scatter epack into the bucket's contiguous 16KB window.
__global__ __launch_bounds__(256) void bucket_fill_kernel(
    const int* __restrict__ rowbase, const uint2* __restrict__ rec,
    unsigned int* __restrict__ epack, int* __restrict__ row_ptr)
{
  __shared__ int off[BK];
  __shared__ int s[256];
  int b = blockIdx.x, t = threadIdx.x;
  int start = rowbase[b];
  int end = rowbase[b + 1];
  int nbase = b * BK;
  off[t] = 0;
  __syncthreads();
  for (int i = start + t; i < end; i += 256)
    atomicAdd(&off[rec[i].x - nbase], 1);
  __syncthreads();
  int v = off[t];
  s[t] = v;
  __syncthreads();
#pragma unroll
  for (int o = 1; o < 256; o <<= 1) {
    int u = (t >= o) ? s[t - o] : 0;
    __syncthreads();
    s[t] += u;
    __syncthreads();
  }
  int ex = s[t] - v;
  int g = nbase + t;
  if (g <= NNODES) row_ptr[g] = start + ex;   // g==NNODES -> start+ex == NEDGES
  __syncthreads();
  off[t] = ex;
  __syncthreads();
  for (int i = start + t; i < end; i += 256) {
    uint2 r = rec[i];
    int lp = atomicAdd(&off[r.x - nbase], 1);
    epack[start + lp] = r.y;
  }
}

// ---------------- bf16 gather aggregation (R3-proven form) ----------------
// agg128: wave per node, quarter-split, 4-deep unroll -> 16 rows in flight/wave.
__global__ __launch_bounds__(256) void agg128_kernel(
    const int* __restrict__ row_ptr, const unsigned int* __restrict__ epack,
    const unsigned short* __restrict__ x, unsigned short* __restrict__ agg)
{
  int node = blockIdx.x * 4 + (threadIdx.x >> 6);
  int lane = threadIdx.x & 63;
  if (node >= NNODES) return;
  int q = lane >> 4, sl = lane & 15;
  int s = row_ptr[node], e = row_ptr[node + 1];
  float acc[8];
#pragma unroll
  for (int j = 0; j < 8; j++) acc[j] = 0.f;

  for (int i = s + q; i < e; i += 16) {
    unsigned int p0 = epack[i];
    unsigned int p1 = (i + 4  < e) ? epack[i + 4]  : 0u;
    unsigned int p2 = (i + 8  < e) ? epack[i + 8]  : 0u;
    unsigned int p3 = (i + 12 < e) ? epack[i + 12] : 0u;
    int s0, s1, s2, s3; float w0, w1, w2, w3;
    unpack_edge(p0, s0, w0);
    unpack_edge(p1, s1, w1);
    unpack_edge(p2, s2, w2);
    unpack_edge(p3, s3, w3);
    ushort8 r0 = *(const ushort8*)(x + (size_t)s0 * 128 + sl * 8);
    ushort8 r1 = *(const ushort8*)(x + (size_t)s1 * 128 + sl * 8);
    ushort8 r2 = *(const ushort8*)(x + (size_t)s2 * 128 + sl * 8);
    ushort8 r3 = *(const ushort8*)(x + (size_t)s3 * 128 + sl * 8);
#pragma unroll
    for (int j = 0; j < 8; j++)
      acc[j] += w0 * b2f(r0[j]) + w1 * b2f(r1[j]) +
                w2 * b2f(r2[j]) + w3 * b2f(r3[j]);
  }
#pragma unroll
  for (int j = 0; j < 8; j++) {
    acc[j] += __shfl_xor(acc[j], 16, 64);
    acc[j] += __shfl_xor(acc[j], 32, 64);
  }
  if (q == 0) {
    ushort8 o;
#pragma unroll
    for (int j = 0; j < 8; j++) o[j] = f2b(acc[j]);
    *(ushort8*)(agg + (size_t)node * 128 + sl * 8) = o;
  }
}

// agg64: wave per node, eighth-split, 2-deep unroll -> 16 rows in flight/wave.
__global__ __launch_bounds__(256) void agg64_kernel(
    const int* __restrict__ row_ptr, const unsigned int* __restrict__ epack,
    const unsigned short* __restrict__ x, unsigned short* __restrict__ agg)
{
  int node = blockIdx.x * 4 + (threadIdx.x >> 6);
  int lane = threadIdx.x & 63;
  if (node >= NNODES) return;
  int q = lane >> 3, sl = lane & 7;
  int s = row_ptr[node], e = row_ptr[node + 1];
  float acc[8];
#pragma unroll
  for (int j = 0; j < 8; j++) acc[j] = 0.f;

  for (int i = s + q; i < e; i += 16) {
    unsigned int p0 = epack[i];
    unsigned int p1 = (i + 8 < e) ? epack[i + 8] : 0u;
    int s0, s1; float w0, w1;
    unpack_edge(p0, s0, w0);
    unpack_edge(p1, s1, w1);
    ushort8 r0 = *(const ushort8*)(x + (size_t)s0 * 64 + sl * 8);
    ushort8 r1 = *(const ushort8*)(x + (size_t)s1 * 64 + sl * 8);
#pragma unroll
    for (int j = 0; j < 8; j++)
      acc[j] += w0 * b2f(r0[j]) + w1 * b2f(r1[j]);
  }
#pragma unroll
  for (int j = 0; j < 8; j++) {
    acc[j] += __shfl_xor(acc[j], 8, 64);
    acc[j] += __shfl_xor(acc[j], 16, 64);
    acc[j] += __shfl_xor(acc[j], 32, 64);
  }
  if (q == 0) {
    ushort8 o;
#pragma unroll
    for (int j = 0; j < 8; j++) o[j] = f2b(acc[j]);
    *(ushort8*)(agg + (size_t)node * 64 + sl * 8) = o;
  }
}

// ---------------- LDS-free MFMA bf16 GEMM (GraphConv layers) ----------------
template <int KDIM, int HOUT, int MT, bool DUAL, bool RELU>
__global__ __launch_bounds__(256) void mfma_gemm(
    const unsigned short* __restrict__ A1, const unsigned short* __restrict__ W1,
    const unsigned short* __restrict__ A2, const unsigned short* __restrict__ W2,
    const float* __restrict__ bias, unsigned short* __restrict__ out)
{
  constexpr int NT2 = HOUT / 16;
  constexpr int KC = KDIM / 32;
  const int wave = threadIdx.x >> 6, lane = threadIdx.x & 63;
  const int quad = lane >> 4, l16 = lane & 15;
  const int n0 = (blockIdx.x * 4 + wave) * (MT * 16);

  f32x4 acc[MT][NT2];
#pragma unroll
  for (int m = 0; m < MT; m++)
#pragma unroll
    for (int t = 0; t < NT2; t++) acc[m][t] = (f32x4){0.f, 0.f, 0.f, 0.f};

  int nodes[MT];
#pragma unroll
  for (int m = 0; m < MT; m++) {
    int nd = n0 + m * 16 + l16;
    nodes[m] = nd < NNODES ? nd : NNODES - 1;
  }

#pragma unroll
  for (int c = 0; c < KC; c++) {
    short8 bfr[NT2];
#pragma unroll
    for (int t = 0; t < NT2; t++)
      bfr[t] = *(const short8*)(W1 + ((size_t)(c * 4 + quad) * HOUT + t * 16 + l16) * 8);
#pragma unroll
    for (int m = 0; m < MT; m++) {
      short8 af = *(const short8*)(A1 + (size_t)nodes[m] * KDIM + c * 32 + quad * 8);
#pragma unroll
      for (int t = 0; t < NT2; t++)
        acc[m][t] = __builtin_amdgcn_mfma_f32_16x16x32_bf16(af, bfr[t], acc[m][t], 0, 0, 0);
    }
    if (DUAL) {
#pragma unroll
      for (int t = 0; t < NT2; t++)
        bfr[t] = *(const short8*)(W2 + ((size_t)(c * 4 + quad) * HOUT + t * 16 + l16) * 8);
#pragma unroll
      for (int m = 0; m < MT; m++) {
        short8 af = *(const short8*)(A2 + (size_t)nodes[m] * KDIM + c * 32 + quad * 8);
#pragma unroll
        for (int t = 0; t < NT2; t++)
          acc[m][t] = __builtin_amdgcn_mfma_f32_16x16x32_bf16(af, bfr[t], acc[m][t], 0, 0, 0);
      }
    }
  }

#pragma unroll
  for (int m = 0; m < MT; m++) {
    int rowbase = n0 + m * 16 + quad * 4;
#pragma unroll
    for (int t = 0; t < NT2; t++) {
      float b = bias[t * 16 + l16];
#pragma unroll
      for (int r = 0; r < 4; r++) {
        int nd = rowbase + r;
        if (nd < NNODES) {
          float v = acc[m][t][r] + b;
          if (RELU) v = fmaxf(v, 0.f);
          out[(size_t)nd * HOUT + t * 16 + l16] = f2b(v);
        }
      }
    }
  }
}

// ---------------- fused readout: GEMM(128->64) + ReLU + dot(Wr2) + segment-sum ----------------
__global__ __launch_bounds__(256) void readout_fused_kernel(
    const unsigned short* __restrict__ A1, const unsigned short* __restrict__ W1,
    const float* __restrict__ br1, const float* __restrict__ Wr2,
    const int* __restrict__ batch, float* __restrict__ gnum)
{
  constexpr int NT2 = 4, KC = 4, MT = 4;
  const int wave = threadIdx.x >> 6, lane = threadIdx.x & 63;
  const int quad = lane >> 4, l16 = lane & 15;
  const int n0 = (blockIdx.x * 4 + wave) * (MT * 16);

  f32x4 acc[MT][NT2];
#pragma unroll
  for (int m = 0; m < MT; m++)
#pragma unroll
    for (int t = 0; t < NT2; t++) acc[m][t] = (f32x4){0.f, 0.f, 0.f, 0.f};

  int nodes[MT];
#pragma unroll
  for (int m = 0; m < MT; m++) {
    int nd = n0 + m * 16 + l16;
    nodes[m] = nd < NNODES ? nd : NNODES - 1;
  }

#pragma unroll
  for (int c = 0; c < KC; c++) {
    short8 bfr[NT2];
#pragma unroll
    for (int t = 0; t < NT2; t++)
      bfr[t] = *(const short8*)(W1 + ((size_t)(c * 4 + quad) * 64 + t * 16 + l16) * 8);
#pragma unroll
    for (int m = 0; m < MT; m++) {
      short8 af = *(const short8*)(A1 + (size_t)nodes[m] * 128 + c * 32 + quad * 8);
#pragma unroll
      for (int t = 0; t < NT2; t++)
        acc[m][t] = __builtin_amdgcn_mfma_f32_16x16x32_bf16(af, bfr[t], acc[m][t], 0, 0, 0);
    }
  }

  float bv[NT2], wv[NT2];
#pragma unroll
  for (int t = 0; t < NT2; t++) {
    bv[t] = br1[t * 16 + l16];
    wv[t] = Wr2[t * 16 + l16];
  }
#pragma unroll
  for (int m = 0; m < MT; m++) {
    int rowbase = n0 + m * 16 + quad * 4;
#pragma unroll
    for (int r = 0; r < 4; r++) {
      float p = 0.f;
#pragma unroll
      for (int t = 0; t < NT2; t++)
        p += fmaxf(acc[m][t][r] + bv[t], 0.f) * wv[t];
      p += __shfl_xor(p, 1, 64);
      p += __shfl_xor(p, 2, 64);
      p += __shfl_xor(p, 4, 64);
      p += __shfl_xor(p, 8, 64);
      int nd = rowbase + r;
      if (l16 == 0 && nd < NNODES)
        atomicAdd(&gnum[batch[nd]], p);
    }
  }
}

__global__ __launch_bounds__(256) void finalize_kernel(
    const float* __restrict__ gnum, const int* __restrict__ gptr,
    const float* __restrict__ br2, float* __restrict__ out)
{
  int g = blockIdx.x * 256 + threadIdx.x;
  if (g >= NGRAPH) return;
  float cnt = (float)(gptr[g + 1] - gptr[g]);
  out[g] = (gnum[g] + cnt * br2[0]) / fmaxf(cnt, 1.f);
}

// ---------------- launch ----------------
extern "C" void kernel_launch(void* const* d_in, const int* in_sizes, int n_in,
                              void* d_out, int out_size, void* d_ws, size_t ws_size,
                              hipStream_t stream)
{
  const float* x      = (const float*)d_in[0];
  const int*   ei     = (const int*)d_in[1];
  const float* ew     = (const float*)d_in[2];
  const int*   batch  = (const int*)d_in[3];
  const float* Wroot0 = (const float*)d_in[4];
  const float* Wrel0  = (const float*)d_in[5];
  const float* b0     = (const float*)d_in[6];
  const float* WrootR = (const float*)d_in[7];
  const float* WrelR  = (const float*)d_in[8];
  const float* bR     = (const float*)d_in[9];
  const float* Wr1    = (const float*)d_in[10];
  const float* br1    = (const float*)d_in[11];
  const float* Wr2    = (const float*)d_in[12];
  const float* br2    = (const float*)d_in[13];

  char* ws = (char*)d_ws;
  unsigned short* wp   = (unsigned short*)ws;                 // 122880 bf16, pad to 131072
  unsigned short* xb   = wp + 131072;                         // N*64 bf16
  unsigned short* agg0 = xb + (size_t)NNODES * 64;            // N*64 bf16 (layer-0 agg)
  unsigned short* bufA = agg0 + (size_t)NNODES * 64;          // N*128 bf16
  unsigned short* bufB = bufA + (size_t)NNODES * 128;         // N*128 bf16
  unsigned short* hbuf = bufB + (size_t)NNODES * 128;         // reused: gnum
  int*  cnt      = (int*)(hbuf + (size_t)NNODES * 64);        // NBE ints (~600KB)
  int*  rowsum   = cnt + ((NBE + 63) & ~63);
  int*  rowbase  = rowsum + NBUCKET + 1;
  int*  row_ptr  = rowbase + NBUCKET + 1;
  int*  gptr     = row_ptr + NNODES + 2;
  unsigned int* epack = (unsigned int*)(gptr + NGRAPH + 2);   // E uint = 6.4MB
  // rec aliases bufA (12.8MB <= 25.6MB); bufA first written by layer-1 agg128,
  // long after bucket_fill_kernel has consumed rec.
  uint2* rec = (uint2*)bufA;
  float* gnum = (float*)hbuf;

  const unsigned short* pWrel0  = wp;
  const unsigned short* pWroot0 = wp + 8192;
  const unsigned short* pWrelR  = wp + 16384;
  const unsigned short* pWrootR = wp + 65536;
  const unsigned short* pWr1    = wp + 114688;

  // fused setup: cvt_x | prepack | gptr | bucket_count | gnum-zero
  setup_kernel<<<SB_TOTAL, 256, 0, stream>>>(
      x, xb, Wrel0, Wroot0, WrelR, WrootR, Wr1, wp, batch, gptr, ei, cnt, gnum);

  // bucketized CSR build (by dst)
  row_scan_kernel<<<NBUCKET, 512, 0, stream>>>(cnt, rowsum);
  rowbase_scan_kernel<<<1, 512, 0, stream>>>(rowsum, rowbase);
  bucket_scatter_kernel<<<NCHUNK, 256, 0, stream>>>(ei, ew, cnt, rowbase, rec);
  bucket_fill_kernel<<<NBUCKET, 256, 0, stream>>>(rowbase, rec, epack, row_ptr);

  // layer 0: 64 -> 128
  agg64_kernel<<<(NNODES + 3) / 4, 256, 0, stream>>>(row_ptr, epack, xb, agg0);
  mfma_gemm<64, 128, 2, true, false><<<(NNODES + 127) / 128, 256, 0, stream>>>(
      agg0, pWrel0, xb, pWroot0, b0, bufB);

  // layers 1..3: 128 -> 128
  unsigned short* bufs[2] = { bufB, bufA };
  for (int l = 0; l < 3; l++) {
    unsigned short* in  = bufs[l & 1];
    unsigned short* agg = bufs[(l & 1) ^ 1];
    agg128_kernel<<<(NNODES + 3) / 4, 256, 0, stream>>>(row_ptr, epack, in, agg);
    mfma_gemm<128, 128, 2, true, false><<<(NNODES + 127) / 128, 256, 0, stream>>>(
        agg, pWrelR + l * 16384, in, pWrootR + l * 16384, bR + l * 128, agg);
  }
  // y3 in bufA

  // fused readout
  readout_fused_kernel<<<(NNODES + 255) / 256, 256, 0, stream>>>(
      bufA, pWr1, br1, Wr2, batch, gnum);
  finalize_kernel<<<(NGRAPH + 255) / 256, 256, 0, stream>>>(gnum, gptr, br2, (float*)d_out);
}

// Round 10
// 490.276 us; speedup vs baseline: 1.2014x; 1.0687x over previous
//
#include <hip/hip_runtime.h>
#include <hip/hip_fp16.h>
#include <cstdint>
#include <cstddef>

#define NNODES 100000
#define NEDGES 1600000
#define NGRAPH 1024

// bucketized CSR build
#define BK 256                             // nodes per bucket (dst >> 8)
#define NBUCKET 391                        // ceil(NNODES / BK)
#define CHUNK 4096
#define NCHUNK 391                         // ceil(NEDGES / CHUNK)
#define NBE (NBUCKET * NCHUNK)             // 152881 count-matrix entries

// setup_kernel block ranges
#define SB_CVT 6250                        // NNODES*64/4/256
#define SB_PRE (SB_CVT + 60)
#define SB_GPTR (SB_PRE + 391)
#define SB_CNT (SB_GPTR + NCHUNK)
#define SB_TOTAL SB_CNT

typedef __attribute__((ext_vector_type(8))) short short8;
typedef __attribute__((ext_vector_type(8))) unsigned short ushort8;
typedef __attribute__((ext_vector_type(4))) float f32x4;

__device__ inline float b2f(unsigned short u) {
  return __uint_as_float(((unsigned int)u) << 16);
}
__device__ inline unsigned short f2b(float f) {
  unsigned int x = __float_as_uint(f);
  x += 0x7fffu + ((x >> 16) & 1u);          // RNE
  return (unsigned short)(x >> 16);
}
// packed edge: (src << 15) | (fp16(weight) >> 1)   [weight >= 0 so sign bit = 0]
__device__ inline unsigned int pack_edge(int src, float w) {
  unsigned short hb = __half_as_ushort(__float2half_rn(w));
  return ((unsigned int)src << 15) | ((unsigned int)hb >> 1);
}
__device__ inline void unpack_edge(unsigned int p, int& src, float& w) {
  src = (int)(p >> 15);
  w = __half2float(__ushort_as_half((unsigned short)((p & 0x7fffu) << 1)));
}

// ---------------- fused setup: cvt_x | prepack | gptr | bucket_count ----------------
// Each block takes exactly one uniform branch -> no divergence hazards.
__global__ __launch_bounds__(256) void setup_kernel(
    const float* __restrict__ x, unsigned short* __restrict__ xb,
    const float* __restrict__ Wrel0, const float* __restrict__ Wroot0,
    const float* __restrict__ WrelR, const float* __restrict__ WrootR,
    const float* __restrict__ Wr1, unsigned short* __restrict__ wp,
    const int* __restrict__ batch, int* __restrict__ gptr,
    const int* __restrict__ ei, int* __restrict__ cnt)
{
  __shared__ int hist[NBUCKET];
  int blk = blockIdx.x;
  if (blk < SB_CVT) {
    // x f32 -> bf16, 4 elems/thread
    int i = blk * 256 + threadIdx.x;
    float4 v = *(const float4*)(x + (size_t)i * 4);
    ushort4 o;
    o.x = f2b(v.x); o.y = f2b(v.y); o.z = f2b(v.z); o.w = f2b(v.w);
    *(ushort4*)(xb + (size_t)i * 4) = o;
  } else if (blk < SB_PRE) {
    // weight prepack: W[HOUT][K] f32 -> bf16 MFMA-B order
    int g = (blk - SB_CVT) * 256 + threadIdx.x;
    if (g >= 15360) return;
    const float* src; int H, K, r; unsigned short* out;
    if (g < 1024)       { src = Wrel0;  H = 128; K = 64;  r = g;        out = wp + r * 8; }
    else if (g < 2048)  { src = Wroot0; H = 128; K = 64;  r = g - 1024; out = wp + 8192 + r * 8; }
    else if (g < 8192)  { int m = g - 2048; int l = m / 2048; r = m % 2048;
                          src = WrelR + l * 16384;  H = 128; K = 128;
                          out = wp + 16384 + l * 16384 + r * 8; }
    else if (g < 14336) { int m = g - 8192; int l = m / 2048; r = m % 2048;
                          src = WrootR + l * 16384; H = 128; K = 128;
                          out = wp + 65536 + l * 16384 + r * 8; }
    else                { src = Wr1;    H = 64;  K = 128; r = g - 14336; out = wp + 114688 + r * 8; }
    int n = r % H, k8 = r / H;
    const float* s = src + (size_t)n * K + k8 * 8;
#pragma unroll
    for (int j = 0; j < 8; j++) out[j] = f2b(s[j]);
  } else if (blk < SB_GPTR) {
    // graph pointer (batch sorted)
    int i = (blk - SB_PRE) * 256 + threadIdx.x;
    if (i >= NNODES) return;
    int b = batch[i];
    int bn = (i + 1 < NNODES) ? batch[i + 1] : NGRAPH;
    for (int g = b + 1; g <= bn; g++) gptr[g] = i + 1;
    if (i == 0) for (int g = 0; g <= b; g++) gptr[g] = 0;
  } else {
    // per-chunk histogram of dst buckets
    int chunk = blk - SB_GPTR;
    for (int i = threadIdx.x; i < NBUCKET; i += 256) hist[i] = 0;
    __syncthreads();
    int base = chunk * CHUNK;
    for (int t = threadIdx.x; t < CHUNK; t += 256) {
      int e = base + t;
      if (e < NEDGES) atomicAdd(&hist[ei[NEDGES + e] >> 8], 1);
    }
    __syncthreads();
    for (int i = threadIdx.x; i < NBUCKET; i += 256)
      cnt[i * NCHUNK + chunk] = hist[i];
  }
}

// ---------------- bucketized CSR build ----------------
// Pass 2a: per-bucket-row exclusive scan (in-row offsets) + row total.
__global__ __launch_bounds__(512) void row_scan_kernel(
    int* __restrict__ cnt, int* __restrict__ rowsum)
{
  __shared__ int s[512];
  int b = blockIdx.x, t = threadIdx.x;
  int v = (t < NCHUNK) ? cnt[b * NCHUNK + t] : 0;
  s[t] = v;
  __syncthreads();
#pragma unroll
  for (int off = 1; off < 512; off <<= 1) {
    int u = (t >= off) ? s[t - off] : 0;
    __syncthreads();
    s[t] += u;
    __syncthreads();
  }
  if (t < NCHUNK) cnt[b * NCHUNK + t] = s[t] - v;
  if (t == 511) rowsum[b] = s[511];
}

// Pass 2b: exclusive scan of the 391 row totals -> rowbase[NBUCKET+1].
__global__ __launch_bounds__(512) void rowbase_scan_kernel(
    const int* __restrict__ rowsum, int* __restrict__ rowbase)
{
  __shared__ int s[512];
  int t = threadIdx.x;
  int v = (t < NBUCKET) ? rowsum[t] : 0;
  s[t] = v;
  __syncthreads();
#pragma unroll
  for (int off = 1; off < 512; off <<= 1) {
    int u = (t >= off) ? s[t - off] : 0;
    __syncthreads();
    s[t] += u;
    __syncthreads();
  }
  if (t < NBUCKET) rowbase[t] = s[t] - v;
  if (t == 511) rowbase[NBUCKET] = s[511];   // == NEDGES
}

// Pass 3: scatter edges into bucket-major record array (dst, packed_edge).
__global__ __launch_bounds__(256) void bucket_scatter_kernel(
    const int* __restrict__ ei, const float* __restrict__ ew,
    const int* __restrict__ cnt, const int* __restrict__ rowbase,
    uint2* __restrict__ rec)
{
  __shared__ int pos[NBUCKET];
  for (int i = threadIdx.x; i < NBUCKET; i += 256)
    pos[i] = rowbase[i] + cnt[i * NCHUNK + blockIdx.x];
  __syncthreads();
  int base = blockIdx.x * CHUNK;
  for (int t = threadIdx.x; t < CHUNK; t += 256) {
    int e = base + t;
    if (e < NEDGES) {
      int d = ei[NEDGES + e];
      int p = atomicAdd(&pos[d >> 8], 1);
      rec[p] = make_uint2((unsigned int)d, pack_edge(ei[e], ew[e]));
    }
  }
}

// Pass 4: one block per bucket. Local degree count + LDS scan writes row_ptr
// directly; then scatter epack into the bucket's contiguous 16KB window.
__global__ __launch_bounds__(256) void bucket_fill_kernel(
    const int* __restrict__ rowbase, const uint2* __restrict__ rec,
    unsigned int* __restrict__ epack, int* __restrict__ row_ptr)
{
  __shared__ int off[BK];
  __shared__ int s[256];
  int b = blockIdx.x, t = threadIdx.x;
  int start = rowbase[b];
  int end = rowbase[b + 1];
  int nbase = b * BK;
  off[t] = 0;
  __syncthreads();
  for (int i = start + t; i < end; i += 256)
    atomicAdd(&off[rec[i].x - nbase], 1);
  __syncthreads();
  int v = off[t];
  s[t] = v;
  __syncthreads();
#pragma unroll
  for (int o = 1; o < 256; o <<= 1) {
    int u = (t >= o) ? s[t - o] : 0;
    __syncthreads();
    s[t] += u;
    __syncthreads();
  }
  int ex = s[t] - v;
  int g = nbase + t;
  if (g <= NNODES) row_ptr[g] = start + ex;   // g==NNODES -> start+ex == NEDGES
  __syncthreads();
  off[t] = ex;
  __syncthreads();
  for (int i = start + t; i < end; i += 256) {
    uint2 r = rec[i];
    int lp = atomicAdd(&off[r.x - nbase], 1);
    epack[start + lp] = r.y;
  }
}

// ---------------- bf16 gather aggregation (R3-proven form) ----------------
// agg128: wave per node, quarter-split, 4-deep unroll -> 16 rows in flight/wave.
__global__ __launch_bounds__(256) void agg128_kernel(
    const int* __restrict__ row_ptr, const unsigned int* __restrict__ epack,
    const unsigned short* __restrict__ x, unsigned short* __restrict__ agg)
{
  int node = blockIdx.x * 4 + (threadIdx.x >> 6);
  int lane = threadIdx.x & 63;
  if (node >= NNODES) return;
  int q = lane >> 4, sl = lane & 15;
  int s = row_ptr[node], e = row_ptr[node + 1];
  float acc[8];
#pragma unroll
  for (int j = 0; j < 8; j++) acc[j] = 0.f;

  for (int i = s + q; i < e; i += 16) {
    unsigned int p0 = epack[i];
    unsigned int p1 = (i + 4  < e) ? epack[i + 4]  : 0u;
    unsigned int p2 = (i + 8  < e) ? epack[i + 8]  : 0u;
    unsigned int p3 = (i + 12 < e) ? epack[i + 12] : 0u;
    int s0, s1, s2, s3; float w0, w1, w2, w3;
    unpack_edge(p0, s0, w0);
    unpack_edge(p1, s1, w1);
    unpack_edge(p2, s2, w2);
    unpack_edge(p3, s3, w3);
    ushort8 r0 = *(const ushort8*)(x + (size_t)s0 * 128 + sl * 8);
    ushort8 r1 = *(const ushort8*)(x + (size_t)s1 * 128 + sl * 8);
    ushort8 r2 = *(const ushort8*)(x + (size_t)s2 * 128 + sl * 8);
    ushort8 r3 = *(const ushort8*)(x + (size_t)s3 * 128 + sl * 8);
#pragma unroll
    for (int j = 0; j < 8; j++)
      acc[j] += w0 * b2f(r0[j]) + w1 * b2f(r1[j]) +
                w2 * b2f(r2[j]) + w3 * b2f(r3[j]);
  }
#pragma unroll
  for (int j = 0; j < 8; j++) {
    acc[j] += __shfl_xor(acc[j], 16, 64);
    acc[j] += __shfl_xor(acc[j], 32, 64);
  }
  if (q == 0) {
    ushort8 o;
#pragma unroll
    for (int j = 0; j < 8; j++) o[j] = f2b(acc[j]);
    *(ushort8*)(agg + (size_t)node * 128 + sl * 8) = o;
  }
}

// agg64: wave per node, eighth-split, 2-deep unroll -> 16 rows in flight/wave.
__global__ __launch_bounds__(256) void agg64_kernel(
    const int* __restrict__ row_ptr, const unsigned int* __restrict__ epack,
    const unsigned short* __restrict__ x, unsigned short* __restrict__ agg)
{
  int node = blockIdx.x * 4 + (threadIdx.x >> 6);
  int lane = threadIdx.x & 63;
  if (node >= NNODES) return;
  int q = lane >> 3, sl = lane & 7;
  int s = row_ptr[node], e = row_ptr[node + 1];
  float acc[8];
#pragma unroll
  for (int j = 0; j < 8; j++) acc[j] = 0.f;

  for (int i = s + q; i < e; i += 16) {
    unsigned int p0 = epack[i];
    unsigned int p1 = (i + 8 < e) ? epack[i + 8] : 0u;
    int s0, s1; float w0, w1;
    unpack_edge(p0, s0, w0);
    unpack_edge(p1, s1, w1);
    ushort8 r0 = *(const ushort8*)(x + (size_t)s0 * 64 + sl * 8);
    ushort8 r1 = *(const ushort8*)(x + (size_t)s1 * 64 + sl * 8);
#pragma unroll
    for (int j = 0; j < 8; j++)
      acc[j] += w0 * b2f(r0[j]) + w1 * b2f(r1[j]);
  }
#pragma unroll
  for (int j = 0; j < 8; j++) {
    acc[j] += __shfl_xor(acc[j], 8, 64);
    acc[j] += __shfl_xor(acc[j], 16, 64);
    acc[j] += __shfl_xor(acc[j], 32, 64);
  }
  if (q == 0) {
    ushort8 o;
#pragma unroll
    for (int j = 0; j < 8; j++) o[j] = f2b(acc[j]);
    *(ushort8*)(agg + (size_t)node * 64 + sl * 8) = o;
  }
}

// ---------------- LDS-free MFMA bf16 GEMM ----------------
template <int KDIM, int HOUT, int MT, bool DUAL, bool RELU>
__global__ __launch_bounds__(256) void mfma_gemm(
    const unsigned short* __restrict__ A1, const unsigned short* __restrict__ W1,
    const unsigned short* __restrict__ A2, const unsigned short* __restrict__ W2,
    const float* __restrict__ bias, unsigned short* __restrict__ out)
{
  constexpr int NT2 = HOUT / 16;
  constexpr int KC = KDIM / 32;
  const int wave = threadIdx.x >> 6, lane = threadIdx.x & 63;
  const int quad = lane >> 4, l16 = lane & 15;
  const int n0 = (blockIdx.x * 4 + wave) * (MT * 16);

  f32x4 acc[MT][NT2];
#pragma unroll
  for (int m = 0; m < MT; m++)
#pragma unroll
    for (int t = 0; t < NT2; t++) acc[m][t] = (f32x4){0.f, 0.f, 0.f, 0.f};

  int nodes[MT];
#pragma unroll
  for (int m = 0; m < MT; m++) {
    int nd = n0 + m * 16 + l16;
    nodes[m] = nd < NNODES ? nd : NNODES - 1;
  }

#pragma unroll
  for (int c = 0; c < KC; c++) {
    short8 bfr[NT2];
#pragma unroll
    for (int t = 0; t < NT2; t++)
      bfr[t] = *(const short8*)(W1 + ((size_t)(c * 4 + quad) * HOUT + t * 16 + l16) * 8);
#pragma unroll
    for (int m = 0; m < MT; m++) {
      short8 af = *(const short8*)(A1 + (size_t)nodes[m] * KDIM + c * 32 + quad * 8);
#pragma unroll
      for (int t = 0; t < NT2; t++)
        acc[m][t] = __builtin_amdgcn_mfma_f32_16x16x32_bf16(af, bfr[t], acc[m][t], 0, 0, 0);
    }
    if (DUAL) {
#pragma unroll
      for (int t = 0; t < NT2; t++)
        bfr[t] = *(const short8*)(W2 + ((size_t)(c * 4 + quad) * HOUT + t * 16 + l16) * 8);
#pragma unroll
      for (int m = 0; m < MT; m++) {
        short8 af = *(const short8*)(A2 + (size_t)nodes[m] * KDIM + c * 32 + quad * 8);
#pragma unroll
        for (int t = 0; t < NT2; t++)
          acc[m][t] = __builtin_amdgcn_mfma_f32_16x16x32_bf16(af, bfr[t], acc[m][t], 0, 0, 0);
      }
    }
  }

#pragma unroll
  for (int m = 0; m < MT; m++) {
    int rowbase = n0 + m * 16 + quad * 4;
#pragma unroll
    for (int t = 0; t < NT2; t++) {
      float b = bias[t * 16 + l16];
#pragma unroll
      for (int r = 0; r < 4; r++) {
        int nd = rowbase + r;
        if (nd < NNODES) {
          float v = acc[m][t][r] + b;
          if (RELU) v = fmaxf(v, 0.f);
          out[(size_t)nd * HOUT + t * 16 + l16] = f2b(v);
        }
      }
    }
  }
}

// ---------------- readout: per-graph block reduction ----------------
__global__ __launch_bounds__(256) void readout_reduce_kernel(
    const unsigned short* __restrict__ h, const float* __restrict__ Wr2,
    const float* __restrict__ br2, const int* __restrict__ gptr,
    float* __restrict__ out)
{
  __shared__ float wsum[4];
  int g = blockIdx.x;
  int s = gptr[g], e = gptr[g + 1];
  int wave = threadIdx.x >> 6, lane = threadIdx.x & 63;
  float w2 = Wr2[lane];
  float acc = 0.f;
  for (int n = s + wave; n < e; n += 4)
    acc += b2f(h[(size_t)n * 64 + lane]) * w2;
#pragma unroll
  for (int off = 32; off >= 1; off >>= 1) acc += __shfl_xor(acc, off, 64);
  if (lane == 0) wsum[wave] = acc;
  __syncthreads();
  if (threadIdx.x == 0) {
    float cnt = (float)(e - s);
    float sum = wsum[0] + wsum[1] + wsum[2] + wsum[3] + cnt * br2[0];
    out[g] = sum / fmaxf(cnt, 1.f);
  }
}

// ---------------- launch ----------------
extern "C" void kernel_launch(void* const* d_in, const int* in_sizes, int n_in,
                              void* d_out, int out_size, void* d_ws, size_t ws_size,
                              hipStream_t stream)
{
  const float* x      = (const float*)d_in[0];
  const int*   ei     = (const int*)d_in[1];
  const float* ew     = (const float*)d_in[2];
  const int*   batch  = (const int*)d_in[3];
  const float* Wroot0 = (const float*)d_in[4];
  const float* Wrel0  = (const float*)d_in[5];
  const float* b0     = (const float*)d_in[6];
  const float* WrootR = (const float*)d_in[7];
  const float* WrelR  = (const float*)d_in[8];
  const float* bR     = (const float*)d_in[9];
  const float* Wr1    = (const float*)d_in[10];
  const float* br1    = (const float*)d_in[11];
  const float* Wr2    = (const float*)d_in[12];
  const float* br2    = (const float*)d_in[13];

  char* ws = (char*)d_ws;
  unsigned short* wp   = (unsigned short*)ws;                 // 122880 bf16, pad to 131072
  unsigned short* xb   = wp + 131072;                         // N*64 bf16
  unsigned short* agg0 = xb + (size_t)NNODES * 64;            // N*64 bf16 (layer-0 agg)
  unsigned short* bufA = agg0 + (size_t)NNODES * 64;          // N*128 bf16
  unsigned short* bufB = bufA + (size_t)NNODES * 128;         // N*128 bf16
  unsigned short* hbuf = bufB + (size_t)NNODES * 128;         // N*64 bf16
  int*  cnt      = (int*)(hbuf + (size_t)NNODES * 64);        // NBE ints (~600KB)
  int*  rowsum   = cnt + ((NBE + 63) & ~63);
  int*  rowbase  = rowsum + NBUCKET + 1;
  int*  row_ptr  = rowbase + NBUCKET + 1;
  int*  gptr     = row_ptr + NNODES + 2;
  unsigned int* epack = (unsigned int*)(gptr + NGRAPH + 2);   // E uint = 6.4MB
  // rec aliases bufA (12.8MB <= 25.6MB); bufA first written by layer-1 agg128,
  // long after bucket_fill_kernel has consumed rec.
  uint2* rec = (uint2*)bufA;

  const unsigned short* pWrel0  = wp;
  const unsigned short* pWroot0 = wp + 8192;
  const unsigned short* pWrelR  = wp + 16384;
  const unsigned short* pWrootR = wp + 65536;
  const unsigned short* pWr1    = wp + 114688;

  // fused setup: cvt_x | prepack | gptr | bucket_count
  setup_kernel<<<SB_TOTAL, 256, 0, stream>>>(
      x, xb, Wrel0, Wroot0, WrelR, WrootR, Wr1, wp, batch, gptr, ei, cnt);

  // bucketized CSR build (by dst)
  row_scan_kernel<<<NBUCKET, 512, 0, stream>>>(cnt, rowsum);
  rowbase_scan_kernel<<<1, 512, 0, stream>>>(rowsum, rowbase);
  bucket_scatter_kernel<<<NCHUNK, 256, 0, stream>>>(ei, ew, cnt, rowbase, rec);
  bucket_fill_kernel<<<NBUCKET, 256, 0, stream>>>(rowbase, rec, epack, row_ptr);

  // layer 0: 64 -> 128
  agg64_kernel<<<(NNODES + 3) / 4, 256, 0, stream>>>(row_ptr, epack, xb, agg0);
  mfma_gemm<64, 128, 2, true, false><<<(NNODES + 127) / 128, 256, 0, stream>>>(
      agg0, pWrel0, xb, pWroot0, b0, bufB);

  // layers 1..3: 128 -> 128
  unsigned short* bufs[2] = { bufB, bufA };
  for (int l = 0; l < 3; l++) {
    unsigned short* in  = bufs[l & 1];
    unsigned short* agg = bufs[(l & 1) ^ 1];
    agg128_kernel<<<(NNODES + 3) / 4, 256, 0, stream>>>(row_ptr, epack, in, agg);
    mfma_gemm<128, 128, 2, true, false><<<(NNODES + 127) / 128, 256, 0, stream>>>(
        agg, pWrelR + l * 16384, in, pWrootR + l * 16384, bR + l * 128, agg);
  }
  // y3 in bufA

  // readout (split, atomic-free: GEMM -> hbuf -> per-graph reduce)
  mfma_gemm<128, 64, 4, false, true><<<(NNODES + 255) / 256, 256, 0, stream>>>(
      bufA, pWr1, nullptr, nullptr, br1, hbuf);
  readout_reduce_kernel<<<NGRAPH, 256, 0, stream>>>(hbuf, Wr2, br2, gptr, (float*)d_out);
}

// Round 11
// 487.450 us; speedup vs baseline: 1.2084x; 1.0058x over previous
//
#include <hip/hip_runtime.h>
#include <hip/hip_fp16.h>
#include <cstdint>
#include <cstddef>

#define NNODES 100000
#define NEDGES 1600000
#define NGRAPH 1024

// bucketized CSR build
#define BK 256                             // nodes per bucket (dst >> 8)
#define NBUCKET 391                        // ceil(NNODES / BK)
#define CHUNK 4096
#define NCHUNK 391                         // ceil(NEDGES / CHUNK)
#define NBE (NBUCKET * NCHUNK)             // 152881 count-matrix entries

// setup_kernel block ranges
#define SB_CVT 6250                        // NNODES*64/4/256
#define SB_PRE (SB_CVT + 60)
#define SB_GPTR (SB_PRE + 391)
#define SB_CNT (SB_GPTR + NCHUNK)
#define SB_TOTAL SB_CNT

typedef __attribute__((ext_vector_type(8))) unsigned short ushort8;
typedef __attribute__((ext_vector_type(8))) _Float16 f16x8;
typedef __attribute__((ext_vector_type(4))) float f32x4;

__device__ inline unsigned short f2h(float f) {
  return __half_as_ushort(__float2half_rn(f));
}
__device__ inline float h2f(unsigned short u) {
  return __half2float(__ushort_as_half(u));
}
// packed edge: (src << 15) | (fp16(weight) >> 1)   [weight >= 0 so sign bit = 0]
__device__ inline unsigned int pack_edge(int src, float w) {
  unsigned short hb = __half_as_ushort(__float2half_rn(w));
  return ((unsigned int)src << 15) | ((unsigned int)hb >> 1);
}
__device__ inline void unpack_edge_h(unsigned int p, int& src, __half2& w2) {
  src = (int)(p >> 15);
  __half wh = __ushort_as_half((unsigned short)((p & 0x7fffu) << 1));
  w2 = __half2half2(wh);
}

// ---------------- fused setup: cvt_x | prepack | gptr | bucket_count ----------------
// Each block takes exactly one uniform branch -> no divergence hazards.
__global__ __launch_bounds__(256) void setup_kernel(
    const float* __restrict__ x, unsigned short* __restrict__ xb,
    const float* __restrict__ Wrel0, const float* __restrict__ Wroot0,
    const float* __restrict__ WrelR, const float* __restrict__ WrootR,
    const float* __restrict__ Wr1, unsigned short* __restrict__ wp,
    const int* __restrict__ batch, int* __restrict__ gptr,
    const int* __restrict__ ei, int* __restrict__ cnt)
{
  __shared__ int hist[NBUCKET];
  int blk = blockIdx.x;
  if (blk < SB_CVT) {
    // x f32 -> fp16, 4 elems/thread
    int i = blk * 256 + threadIdx.x;
    float4 v = *(const float4*)(x + (size_t)i * 4);
    ushort4 o;
    o.x = f2h(v.x); o.y = f2h(v.y); o.z = f2h(v.z); o.w = f2h(v.w);
    *(ushort4*)(xb + (size_t)i * 4) = o;
  } else if (blk < SB_PRE) {
    // weight prepack: W[HOUT][K] f32 -> fp16 MFMA-B order
    int g = (blk - SB_CVT) * 256 + threadIdx.x;
    if (g >= 15360) return;
    const float* src; int H, K, r; unsigned short* out;
    if (g < 1024)       { src = Wrel0;  H = 128; K = 64;  r = g;        out = wp + r * 8; }
    else if (g < 2048)  { src = Wroot0; H = 128; K = 64;  r = g - 1024; out = wp + 8192 + r * 8; }
    else if (g < 8192)  { int m = g - 2048; int l = m / 2048; r = m % 2048;
                          src = WrelR + l * 16384;  H = 128; K = 128;
                          out = wp + 16384 + l * 16384 + r * 8; }
    else if (g < 14336) { int m = g - 8192; int l = m / 2048; r = m % 2048;
                          src = WrootR + l * 16384; H = 128; K = 128;
                          out = wp + 65536 + l * 16384 + r * 8; }
    else                { src = Wr1;    H = 64;  K = 128; r = g - 14336; out = wp + 114688 + r * 8; }
    int n = r % H, k8 = r / H;
    const float* s = src + (size_t)n * K + k8 * 8;
#pragma unroll
    for (int j = 0; j < 8; j++) out[j] = f2h(s[j]);
  } else if (blk < SB_GPTR) {
    // graph pointer (batch sorted)
    int i = (blk - SB_PRE) * 256 + threadIdx.x;
    if (i >= NNODES) return;
    int b = batch[i];
    int bn = (i + 1 < NNODES) ? batch[i + 1] : NGRAPH;
    for (int g = b + 1; g <= bn; g++) gptr[g] = i + 1;
    if (i == 0) for (int g = 0; g <= b; g++) gptr[g] = 0;
  } else {
    // per-chunk histogram of dst buckets
    int chunk = blk - SB_GPTR;
    for (int i = threadIdx.x; i < NBUCKET; i += 256) hist[i] = 0;
    __syncthreads();
    int base = chunk * CHUNK;
    for (int t = threadIdx.x; t < CHUNK; t += 256) {
      int e = base + t;
      if (e < NEDGES) atomicAdd(&hist[ei[NEDGES + e] >> 8], 1);
    }
    __syncthreads();
    for (int i = threadIdx.x; i < NBUCKET; i += 256)
      cnt[i * NCHUNK + chunk] = hist[i];
  }
}

// ---------------- bucketized CSR build ----------------
// Pass 2a: per-bucket-row exclusive scan (in-row offsets) + row total.
__global__ __launch_bounds__(512) void row_scan_kernel(
    int* __restrict__ cnt, int* __restrict__ rowsum)
{
  __shared__ int s[512];
  int b = blockIdx.x, t = threadIdx.x;
  int v = (t < NCHUNK) ? cnt[b * NCHUNK + t] : 0;
  s[t] = v;
  __syncthreads();
#pragma unroll
  for (int off = 1; off < 512; off <<= 1) {
    int u = (t >= off) ? s[t - off] : 0;
    __syncthreads();
    s[t] += u;
    __syncthreads();
  }
  if (t < NCHUNK) cnt[b * NCHUNK + t] = s[t] - v;
  if (t == 511) rowsum[b] = s[511];
}

// Pass 2b: exclusive scan of the 391 row totals -> rowbase[NBUCKET+1].
__global__ __launch_bounds__(512) void rowbase_scan_kernel(
    const int* __restrict__ rowsum, int* __restrict__ rowbase)
{
  __shared__ int s[512];
  int t = threadIdx.x;
  int v = (t < NBUCKET) ? rowsum[t] : 0;
  s[t] = v;
  __syncthreads();
#pragma unroll
  for (int off = 1; off < 512; off <<= 1) {
    int u = (t >= off) ? s[t - off] : 0;
    __syncthreads();
    s[t] += u;
    __syncthreads();
  }
  if (t < NBUCKET) rowbase[t] = s[t] - v;
  if (t == 511) rowbase[NBUCKET] = s[511];   // == NEDGES
}

// Pass 3: scatter edges into bucket-major record array (dst, packed_edge).
__global__ __launch_bounds__(256) void bucket_scatter_kernel(
    const int* __restrict__ ei, const float* __restrict__ ew,
    const int* __restrict__ cnt, const int* __restrict__ rowbase,
    uint2* __restrict__ rec)
{
  __shared__ int pos[NBUCKET];
  for (int i = threadIdx.x; i < NBUCKET; i += 256)
    pos[i] = rowbase[i] + cnt[i * NCHUNK + blockIdx.x];
  __syncthreads();
  int base = blockIdx.x * CHUNK;
  for (int t = threadIdx.x; t < CHUNK; t += 256) {
    int e = base + t;
    if (e < NEDGES) {
      int d = ei[NEDGES + e];
      int p = atomicAdd(&pos[d >> 8], 1);
      rec[p] = make_uint2((unsigned int)d, pack_edge(ei[e], ew[e]));
    }
  }
}

// Pass 4: one block per bucket. Local degree count + LDS scan writes row_ptr
// directly; then scatter epack into the bucket's contiguous 16KB window.
__global__ __launch_bounds__(256) void bucket_fill_kernel(
    const int* __restrict__ rowbase, const uint2* __restrict__ rec,
    unsigned int* __restrict__ epack, int* __restrict__ row_ptr)
{
  __shared__ int off[BK];
  __shared__ int s[256];
  int b = blockIdx.x, t = threadIdx.x;
  int start = rowbase[b];
  int end = rowbase[b + 1];
  int nbase = b * BK;
  off[t] = 0;
  __syncthreads();
  for (int i = start + t; i < end; i += 256)
    atomicAdd(&off[rec[i].x - nbase], 1);
  __syncthreads();
  int v = off[t];
  s[t] = v;
  __syncthreads();
#pragma unroll
  for (int o = 1; o < 256; o <<= 1) {
    int u = (t >= o) ? s[t - o] : 0;
    __syncthreads();
    s[t] += u;
    __syncthreads();
  }
  int ex = s[t] - v;
  int g = nbase + t;
  if (g <= NNODES) row_ptr[g] = start + ex;   // g==NNODES -> start+ex == NEDGES
  __syncthreads();
  off[t] = ex;
  __syncthreads();
  for (int i = start + t; i < end; i += 256) {
    uint2 r = rec[i];
    int lp = atomicAdd(&off[r.x - nbase], 1);
    epack[start + lp] = r.y;
  }
}

// ---------------- fp16 gather aggregation (R3-proven shape, packed math) ----------------
// agg128: wave per node, quarter-split, 4-deep unroll -> 16 rows in flight/wave.
// Inner loop uses __hfma2 (v_pk_fma_f16): 4 ops per 8 elems, no converts.
// Per-lane fp16 accumulation spans only ~deg/4 terms; cross-lane reduce in f32.
__global__ __launch_bounds__(256) void agg128_kernel(
    const int* __restrict__ row_ptr, const unsigned int* __restrict__ epack,
    const unsigned short* __restrict__ x, unsigned short* __restrict__ agg)
{
  int node = blockIdx.x * 4 + (threadIdx.x >> 6);
  int lane = threadIdx.x & 63;
  if (node >= NNODES) return;
  int q = lane >> 4, sl = lane & 15;
  int s = row_ptr[node], e = row_ptr[node + 1];
  __half2 acch[4];
#pragma unroll
  for (int k = 0; k < 4; k++) acch[k] = __half2half2(__ushort_as_half(0));

  union HU { ushort8 u; __half2 h[4]; };
  for (int i = s + q; i < e; i += 16) {
    unsigned int p0 = epack[i];
    unsigned int p1 = (i + 4  < e) ? epack[i + 4]  : 0u;
    unsigned int p2 = (i + 8  < e) ? epack[i + 8]  : 0u;
    unsigned int p3 = (i + 12 < e) ? epack[i + 12] : 0u;
    int s0, s1, s2, s3; __half2 wA, wB, wC, wD;
    unpack_edge_h(p0, s0, wA);
    unpack_edge_h(p1, s1, wB);
    unpack_edge_h(p2, s2, wC);
    unpack_edge_h(p3, s3, wD);
    HU r0, r1, r2, r3;
    r0.u = *(const ushort8*)(x + (size_t)s0 * 128 + sl * 8);
    r1.u = *(const ushort8*)(x + (size_t)s1 * 128 + sl * 8);
    r2.u = *(const ushort8*)(x + (size_t)s2 * 128 + sl * 8);
    r3.u = *(const ushort8*)(x + (size_t)s3 * 128 + sl * 8);
#pragma unroll
    for (int k = 0; k < 4; k++) {
      acch[k] = __hfma2(wA, r0.h[k], acch[k]);
      acch[k] = __hfma2(wB, r1.h[k], acch[k]);
      acch[k] = __hfma2(wC, r2.h[k], acch[k]);
      acch[k] = __hfma2(wD, r3.h[k], acch[k]);
    }
  }
  float acc[8];
#pragma unroll
  for (int k = 0; k < 4; k++) {
    acc[2 * k]     = __low2float(acch[k]);
    acc[2 * k + 1] = __high2float(acch[k]);
  }
#pragma unroll
  for (int j = 0; j < 8; j++) {
    acc[j] += __shfl_xor(acc[j], 16, 64);
    acc[j] += __shfl_xor(acc[j], 32, 64);
  }
  if (q == 0) {
    ushort8 o;
#pragma unroll
    for (int j = 0; j < 8; j++) o[j] = f2h(acc[j]);
    *(ushort8*)(agg + (size_t)node * 128 + sl * 8) = o;
  }
}

// agg64: wave per node, eighth-split, 2-deep unroll, packed fp16 math.
__global__ __launch_bounds__(256) void agg64_kernel(
    const int* __restrict__ row_ptr, const unsigned int* __restrict__ epack,
    const unsigned short* __restrict__ x, unsigned short* __restrict__ agg)
{
  int node = blockIdx.x * 4 + (threadIdx.x >> 6);
  int lane = threadIdx.x & 63;
  if (node >= NNODES) return;
  int q = lane >> 3, sl = lane & 7;
  int s = row_ptr[node], e = row_ptr[node + 1];
  __half2 acch[4];
#pragma unroll
  for (int k = 0; k < 4; k++) acch[k] = __half2half2(__ushort_as_half(0));

  union HU { ushort8 u; __half2 h[4]; };
  for (int i = s + q; i < e; i += 16) {
    unsigned int p0 = epack[i];
    unsigned int p1 = (i + 8 < e) ? epack[i + 8] : 0u;
    int s0, s1; __half2 wA, wB;
    unpack_edge_h(p0, s0, wA);
    unpack_edge_h(p1, s1, wB);
    HU r0, r1;
    r0.u = *(const ushort8*)(x + (size_t)s0 * 64 + sl * 8);
    r1.u = *(const ushort8*)(x + (size_t)s1 * 64 + sl * 8);
#pragma unroll
    for (int k = 0; k < 4; k++) {
      acch[k] = __hfma2(wA, r0.h[k], acch[k]);
      acch[k] = __hfma2(wB, r1.h[k], acch[k]);
    }
  }
  float acc[8];
#pragma unroll
  for (int k = 0; k < 4; k++) {
    acc[2 * k]     = __low2float(acch[k]);
    acc[2 * k + 1] = __high2float(acch[k]);
  }
#pragma unroll
  for (int j = 0; j < 8; j++) {
    acc[j] += __shfl_xor(acc[j], 8, 64);
    acc[j] += __shfl_xor(acc[j], 16, 64);
    acc[j] += __shfl_xor(acc[j], 32, 64);
  }
  if (q == 0) {
    ushort8 o;
#pragma unroll
    for (int j = 0; j < 8; j++) o[j] = f2h(acc[j]);
    *(ushort8*)(agg + (size_t)node * 64 + sl * 8) = o;
  }
}

// ---------------- LDS-free MFMA fp16 GEMM ----------------
template <int KDIM, int HOUT, int MT, bool DUAL, bool RELU>
__global__ __launch_bounds__(256) void mfma_gemm(
    const unsigned short* __restrict__ A1, const unsigned short* __restrict__ W1,
    const unsigned short* __restrict__ A2, const unsigned short* __restrict__ W2,
    const float* __restrict__ bias, unsigned short* __restrict__ out)
{
  constexpr int NT2 = HOUT / 16;
  constexpr int KC = KDIM / 32;
  const int wave = threadIdx.x >> 6, lane = threadIdx.x & 63;
  const int quad = lane >> 4, l16 = lane & 15;
  const int n0 = (blockIdx.x * 4 + wave) * (MT * 16);

  f32x4 acc[MT][NT2];
#pragma unroll
  for (int m = 0; m < MT; m++)
#pragma unroll
    for (int t = 0; t < NT2; t++) acc[m][t] = (f32x4){0.f, 0.f, 0.f, 0.f};

  int nodes[MT];
#pragma unroll
  for (int m = 0; m < MT; m++) {
    int nd = n0 + m * 16 + l16;
    nodes[m] = nd < NNODES ? nd : NNODES - 1;
  }

#pragma unroll
  for (int c = 0; c < KC; c++) {
    f16x8 bfr[NT2];
#pragma unroll
    for (int t = 0; t < NT2; t++)
      bfr[t] = *(const f16x8*)(W1 + ((size_t)(c * 4 + quad) * HOUT + t * 16 + l16) * 8);
#pragma unroll
    for (int m = 0; m < MT; m++) {
      f16x8 af = *(const f16x8*)(A1 + (size_t)nodes[m] * KDIM + c * 32 + quad * 8);
#pragma unroll
      for (int t = 0; t < NT2; t++)
        acc[m][t] = __builtin_amdgcn_mfma_f32_16x16x32_f16(af, bfr[t], acc[m][t], 0, 0, 0);
    }
    if (DUAL) {
#pragma unroll
      for (int t = 0; t < NT2; t++)
        bfr[t] = *(const f16x8*)(W2 + ((size_t)(c * 4 + quad) * HOUT + t * 16 + l16) * 8);
#pragma unroll
      for (int m = 0; m < MT; m++) {
        f16x8 af = *(const f16x8*)(A2 + (size_t)nodes[m] * KDIM + c * 32 + quad * 8);
#pragma unroll
        for (int t = 0; t < NT2; t++)
          acc[m][t] = __builtin_amdgcn_mfma_f32_16x16x32_f16(af, bfr[t], acc[m][t], 0, 0, 0);
      }
    }
  }

#pragma unroll
  for (int m = 0; m < MT; m++) {
    int rowbase = n0 + m * 16 + quad * 4;
#pragma unroll
    for (int t = 0; t < NT2; t++) {
      float b = bias[t * 16 + l16];
#pragma unroll
      for (int r = 0; r < 4; r++) {
        int nd = rowbase + r;
        if (nd < NNODES) {
          float v = acc[m][t][r] + b;
          if (RELU) v = fmaxf(v, 0.f);
          out[(size_t)nd * HOUT + t * 16 + l16] = f2h(v);
        }
      }
    }
  }
}

// ---------------- readout: per-graph block reduction ----------------
__global__ __launch_bounds__(256) void readout_reduce_kernel(
    const unsigned short* __restrict__ h, const float* __restrict__ Wr2,
    const float* __restrict__ br2, const int* __restrict__ gptr,
    float* __restrict__ out)
{
  __shared__ float wsum[4];
  int g = blockIdx.x;
  int s = gptr[g], e = gptr[g + 1];
  int wave = threadIdx.x >> 6, lane = threadIdx.x & 63;
  float w2 = Wr2[lane];
  float acc = 0.f;
  for (int n = s + wave; n < e; n += 4)
    acc += h2f(h[(size_t)n * 64 + lane]) * w2;
#pragma unroll
  for (int off = 32; off >= 1; off >>= 1) acc += __shfl_xor(acc, off, 64);
  if (lane == 0) wsum[wave] = acc;
  __syncthreads();
  if (threadIdx.x == 0) {
    float cnt = (float)(e - s);
    float sum = wsum[0] + wsum[1] + wsum[2] + wsum[3] + cnt * br2[0];
    out[g] = sum / fmaxf(cnt, 1.f);
  }
}

// ---------------- launch ----------------
extern "C" void kernel_launch(void* const* d_in, const int* in_sizes, int n_in,
                              void* d_out, int out_size, void* d_ws, size_t ws_size,
                              hipStream_t stream)
{
  const float* x      = (const float*)d_in[0];
  const int*   ei     = (const int*)d_in[1];
  const float* ew     = (const float*)d_in[2];
  const int*   batch  = (const int*)d_in[3];
  const float* Wroot0 = (const float*)d_in[4];
  const float* Wrel0  = (const float*)d_in[5];
  const float* b0     = (const float*)d_in[6];
  const float* WrootR = (const float*)d_in[7];
  const float* WrelR  = (const float*)d_in[8];
  const float* bR     = (const float*)d_in[9];
  const float* Wr1    = (const float*)d_in[10];
  const float* br1    = (const float*)d_in[11];
  const float* Wr2    = (const float*)d_in[12];
  const float* br2    = (const float*)d_in[13];

  char* ws = (char*)d_ws;
  unsigned short* wp   = (unsigned short*)ws;                 // 122880 fp16, pad to 131072
  unsigned short* xb   = wp + 131072;                         // N*64 fp16
  unsigned short* agg0 = xb + (size_t)NNODES * 64;            // N*64 fp16 (layer-0 agg)
  unsigned short* bufA = agg0 + (size_t)NNODES * 64;          // N*128 fp16
  unsigned short* bufB = bufA + (size_t)NNODES * 128;         // N*128 fp16
  unsigned short* hbuf = bufB + (size_t)NNODES * 128;         // N*64 fp16
  int*  cnt      = (int*)(hbuf + (size_t)NNODES * 64);        // NBE ints (~600KB)
  int*  rowsum   = cnt + ((NBE + 63) & ~63);
  int*  rowbase  = rowsum + NBUCKET + 1;
  int*  row_ptr  = rowbase + NBUCKET + 1;
  int*  gptr     = row_ptr + NNODES + 2;
  unsigned int* epack = (unsigned int*)(gptr + NGRAPH + 2);   // E uint = 6.4MB
  // rec aliases bufA (12.8MB <= 25.6MB); bufA first written by layer-1 agg128,
  // long after bucket_fill_kernel has consumed rec.
  uint2* rec = (uint2*)bufA;

  const unsigned short* pWrel0  = wp;
  const unsigned short* pWroot0 = wp + 8192;
  const unsigned short* pWrelR  = wp + 16384;
  const unsigned short* pWrootR = wp + 65536;
  const unsigned short* pWr1    = wp + 114688;

  // fused setup: cvt_x | prepack | gptr | bucket_count
  setup_kernel<<<SB_TOTAL, 256, 0, stream>>>(
      x, xb, Wrel0, Wroot0, WrelR, WrootR, Wr1, wp, batch, gptr, ei, cnt);

  // bucketized CSR build (by dst)
  row_scan_kernel<<<NBUCKET, 512, 0, stream>>>(cnt, rowsum);
  rowbase_scan_kernel<<<1, 512, 0, stream>>>(rowsum, rowbase);
  bucket_scatter_kernel<<<NCHUNK, 256, 0, stream>>>(ei, ew, cnt, rowbase, rec);
  bucket_fill_kernel<<<NBUCKET, 256, 0, stream>>>(rowbase, rec, epack, row_ptr);

  // layer 0: 64 -> 128
  agg64_kernel<<<(NNODES + 3) / 4, 256, 0, stream>>>(row_ptr, epack, xb, agg0);
  mfma_gemm<64, 128, 2, true, false><<<(NNODES + 127) / 128, 256, 0, stream>>>(
      agg0, pWrel0, xb, pWroot0, b0, bufB);

  // layers 1..3: 128 -> 128
  unsigned short* bufs[2] = { bufB, bufA };
  for (int l = 0; l < 3; l++) {
    unsigned short* in  = bufs[l & 1];
    unsigned short* agg = bufs[(l & 1) ^ 1];
    agg128_kernel<<<(NNODES + 3) / 4, 256, 0, stream>>>(row_ptr, epack, in, agg);
    mfma_gemm<128, 128, 2, true, false><<<(NNODES + 127) / 128, 256, 0, stream>>>(
        agg, pWrelR + l * 16384, in, pWrootR + l * 16384, bR + l * 128, agg);
  }
  // y3 in bufA

  // readout (split, atomic-free: GEMM -> hbuf -> per-graph reduce)
  mfma_gemm<128, 64, 4, false, true><<<(NNODES + 255) / 256, 256, 0, stream>>>(
      bufA, pWr1, nullptr, nullptr, br1, hbuf);
  readout_reduce_kernel<<<NGRAPH, 256, 0, stream>>>(hbuf, Wr2, br2, gptr, (float*)d_out);
}